// Round 4
// baseline (882.479 us; speedup 1.0000x reference)
//
#include <hip/hip_runtime.h>
#include <hip/hip_bf16.h>

// DynaLoRALinear via K-augmented bf16 GEMM:
//   x_aug[row][0:4096]=bf16(x), [4096:4128]=gate*t (LoRA-A MFMA GEMM), [4128:4160]=0
//   W_aug[o][0:4096]=bf16(W_base), [4096+e*8+r]=bf16(lora_B[e,o,r]), rest 0
//   out = x_aug @ W_aug^T + b_base   (M=16384, N=4096, K=4160)
// Main GEMM: 256x256 tile, 8 waves (2Mx4N), K processed in 32-wide half-groups,
// LDS ring of 4 slots (A+B 16KB each), 2 phases/group {ds_read || stage ->
// barrier -> lgkmcnt(0) -> 16 MFMA -> barrier}, one counted vmcnt(8)/group
// (3 groups prefetch in flight, never drained), T2 swizzle, T5 setprio, T1 XCD.

typedef short short8 __attribute__((ext_vector_type(8)));
typedef float f32x4v __attribute__((ext_vector_type(4)));

#define M_DIM 16384
#define N_DIM 4096
#define K_DIM 4160   // 65 * 64 = 130 * 32
#define D_DIM 4096
#define NGRP 130     // 32-wide K groups

__device__ __forceinline__ unsigned short f2b(float f) {
  unsigned u = __builtin_bit_cast(unsigned, f);
  return (unsigned short)((u + 0x7FFFu + ((u >> 16) & 1u)) >> 16);  // RNE
}
__device__ __forceinline__ void async_copy16(void* lds, const void* g) {
  __builtin_amdgcn_global_load_lds(
      (const __attribute__((address_space(1))) void*)g,
      (__attribute__((address_space(3))) void*)lds, 16, 0, 0);
}
// 64-col (128 B-row) LDS tiles used by lora_t_k: phys slot p of row r holds
// logical l = p ^ (r&7); read logical l at p = l ^ (r&7).
__device__ __forceinline__ short8 frag_ld(const short* base, int row, int ks, int hi, int lo) {
  return *(const short8*)(&base[row * 64 + (((ks * 4 + hi) ^ (lo & 7)) * 8)]);
}

// ---- K1: x (f32) -> x_aug (bf16, stride 4160), zero cols 4096..4159
__global__ __launch_bounds__(256) void cvt_x_k(const float* __restrict__ x,
                                               short* __restrict__ xa) {
  size_t idx = (size_t)blockIdx.x * 256 + threadIdx.x;   // 16384*520
  size_t row = idx / 520;
  int cc = (int)(idx % 520);
  short8 o;
  if (cc < 512) {
    const float* src = x + row * (size_t)D_DIM + (size_t)cc * 8;
    float4 a = *(const float4*)(src);
    float4 b = *(const float4*)(src + 4);
    o[0] = (short)f2b(a.x); o[1] = (short)f2b(a.y);
    o[2] = (short)f2b(a.z); o[3] = (short)f2b(a.w);
    o[4] = (short)f2b(b.x); o[5] = (short)f2b(b.y);
    o[6] = (short)f2b(b.z); o[7] = (short)f2b(b.w);
  } else {
#pragma unroll
    for (int t = 0; t < 8; ++t) o[t] = 0;
  }
  *(short8*)(xa + row * (size_t)K_DIM + (size_t)cc * 8) = o;
}

// ---- K2: W_base -> W_aug, pack lora_B into cols 4096..4127, zero rest
__global__ __launch_bounds__(256) void cvt_w_k(const float* __restrict__ Wb,
                                               const float* __restrict__ lB,
                                               short* __restrict__ wa) {
  size_t idx = (size_t)blockIdx.x * 256 + threadIdx.x;   // 4096*520
  size_t row = idx / 520;
  int cc = (int)(idx % 520);
  short8 o;
  if (cc < 512) {
    const float* src = Wb + row * (size_t)D_DIM + (size_t)cc * 8;
    float4 a = *(const float4*)(src);
    float4 b = *(const float4*)(src + 4);
    o[0] = (short)f2b(a.x); o[1] = (short)f2b(a.y);
    o[2] = (short)f2b(a.z); o[3] = (short)f2b(a.w);
    o[4] = (short)f2b(b.x); o[5] = (short)f2b(b.y);
    o[6] = (short)f2b(b.z); o[7] = (short)f2b(b.w);
  } else if (cc < 516) {
    int e = cc - 512;
    const float* src = lB + (size_t)e * (D_DIM * 8) + row * 8;
    float4 a = *(const float4*)(src);
    float4 b = *(const float4*)(src + 4);
    o[0] = (short)f2b(a.x); o[1] = (short)f2b(a.y);
    o[2] = (short)f2b(a.z); o[3] = (short)f2b(a.w);
    o[4] = (short)f2b(b.x); o[5] = (short)f2b(b.y);
    o[6] = (short)f2b(b.z); o[7] = (short)f2b(b.w);
  } else {
#pragma unroll
    for (int t = 0; t < 8; ++t) o[t] = 0;
  }
  *(short8*)(wa + row * (size_t)K_DIM + (size_t)cc * 8) = o;
}

// ---- K2b: lora_A (f32 [32][4096]) -> bf16
__global__ __launch_bounds__(256) void cvt_la_k(const float* __restrict__ lA,
                                                short* __restrict__ lAb) {
  size_t i = (size_t)blockIdx.x * 256 + threadIdx.x;
  const float* s = lA + i * 8;
  float4 a = *(const float4*)s;
  float4 b = *(const float4*)(s + 4);
  short8 o;
  o[0] = (short)f2b(a.x); o[1] = (short)f2b(a.y);
  o[2] = (short)f2b(a.z); o[3] = (short)f2b(a.w);
  o[4] = (short)f2b(b.x); o[5] = (short)f2b(b.y);
  o[6] = (short)f2b(b.z); o[7] = (short)f2b(b.w);
  *(short8*)(lAb + i * 8) = o;
}

// ---- K3: gated[b][j] = dot(x[b,L-1,:], gating_W[j,:]) (exact f32 path)
__global__ __launch_bounds__(256) void gated_k(const float* __restrict__ x,
                                               const float* __restrict__ gW,
                                               float* __restrict__ gated) {
  const int j = blockIdx.x;
  const int tid = threadIdx.x;
  float acc[8];
#pragma unroll
  for (int b = 0; b < 8; ++b) acc[b] = 0.f;
  const float* w = gW + (size_t)j * D_DIM;
  for (int i = tid * 4; i < D_DIM; i += 1024) {
    float4 wv = *(const float4*)(w + i);
#pragma unroll
    for (int b = 0; b < 8; ++b) {
      const float* p = x + ((size_t)b * 2048 + 2047) * D_DIM + i;
      float4 pv = *(const float4*)p;
      acc[b] += wv.x * pv.x + wv.y * pv.y + wv.z * pv.z + wv.w * pv.w;
    }
  }
  __shared__ float red[8][4];
  const int lane = tid & 63, wv_ = tid >> 6;
#pragma unroll
  for (int b = 0; b < 8; ++b) {
    float v = acc[b];
    v += __shfl_down(v, 32); v += __shfl_down(v, 16); v += __shfl_down(v, 8);
    v += __shfl_down(v, 4);  v += __shfl_down(v, 2);  v += __shfl_down(v, 1);
    if (lane == 0) red[b][wv_] = v;
  }
  __syncthreads();
  if (tid < 8)
    gated[(size_t)tid * D_DIM + j] = red[tid][0] + red[tid][1] + red[tid][2] + red[tid][3];
}

// ---- K4: logits -> softmax -> module_prob -> top-k gate (1 wave)
__global__ void gate_k(const float* __restrict__ gated, const float* __restrict__ Wr,
                       const float* __restrict__ scores, const int* __restrict__ midx_p,
                       const int* __restrict__ kp, float* __restrict__ gate) {
  const int lane = threadIdx.x;
  float acc[56];
#pragma unroll
  for (int t = 0; t < 56; ++t) acc[t] = 0.f;
  for (int i = lane * 4; i < D_DIM; i += 256) {
    float4 g[8]; float4 w[7];
#pragma unroll
    for (int b = 0; b < 8; ++b) g[b] = *(const float4*)(gated + (size_t)b * D_DIM + i);
#pragma unroll
    for (int m = 0; m < 7; ++m) w[m] = *(const float4*)(Wr + (size_t)m * D_DIM + i);
#pragma unroll
    for (int m = 0; m < 7; ++m)
#pragma unroll
      for (int b = 0; b < 8; ++b)
        acc[m * 8 + b] += w[m].x * g[b].x + w[m].y * g[b].y + w[m].z * g[b].z + w[m].w * g[b].w;
  }
  __shared__ float Ls[56];
#pragma unroll
  for (int t = 0; t < 56; ++t) {
    float v = acc[t];
    v += __shfl_xor(v, 1); v += __shfl_xor(v, 2); v += __shfl_xor(v, 4);
    v += __shfl_xor(v, 8); v += __shfl_xor(v, 16); v += __shfl_xor(v, 32);
    if (lane == t) Ls[t] = v;
  }
  __syncthreads();
  if (lane < 8) {
    const int b = lane;
    float mx = -1e30f;
    for (int m = 0; m < 7; ++m) mx = fmaxf(mx, Ls[m * 8 + b]);
    float s = 0.f;
    for (int m = 0; m < 7; ++m) s += expf(Ls[m * 8 + b] - mx);
    const int mi = midx_p[0];
    const float mp = expf(Ls[mi * 8 + b] - mx) / s;
    int kv = kp[0]; if (kv < 1) kv = 1;
    int klo = kv >> 1; if (klo < 1) klo = 1;
    float sc[4];
#pragma unroll
    for (int e = 0; e < 4; ++e) sc[e] = scores[b * 4 + e];
#pragma unroll
    for (int e = 0; e < 4; ++e) {
      int rank = 0;
#pragma unroll
      for (int e2 = 0; e2 < 4; ++e2)
        rank += (sc[e2] > sc[e] || (sc[e2] == sc[e] && e2 < e)) ? 1 : 0;
      float wv = (mp > 0.5f) ? ((rank < kv) ? 1.0f / (float)kv : 0.f)
                             : ((rank < klo) ? 1.0f / (float)klo : 0.f);
      gate[b * 4 + e] = wv;
    }
  }
}

// ---- K5: LoRA-A projection as MFMA GEMM: t = xa[:, :4096] @ lAb^T (N=32),
// scaled by gate, written bf16 into xa cols 4096..4127. (R3 version, passed.)
__global__ __launch_bounds__(256) void lora_t_k(const short* __restrict__ XA,
                                                const short* __restrict__ LAb,
                                                const float* __restrict__ gate,
                                                short* __restrict__ xa_w) {
  __shared__ short As[4096];   // 64 x 64 bf16
  __shared__ short Bs[2048];   // 32 x 64 bf16
  const int tid = threadIdx.x, lane = tid & 63, wave = tid >> 6;
  const int lo = lane & 15, hi = lane >> 4;
  const size_t row0 = (size_t)blockIdx.x * 64;
  const int srow = tid >> 3;
  const int slot = (tid & 7) ^ (srow & 7);
  const short* gA = XA + (row0 + srow) * (size_t)K_DIM + slot * 8;
  const short* gB = LAb + (size_t)srow * D_DIM + slot * 8;
  f32x4v acc[2] = {};

  for (int t = 0; t < 64; ++t) {
    const int kt = t * 64;
    char* la = (char*)As + wave * 1024;
    char* lb = (char*)Bs + wave * 1024;
    async_copy16(la, gA + kt);
    async_copy16(la + 4096, gA + (size_t)32 * K_DIM + kt);
    async_copy16(lb, gB + kt);
    __syncthreads();
    short8 a0 = frag_ld(As, wave * 16 + lo, 0, hi, lo);
    short8 a1 = frag_ld(As, wave * 16 + lo, 1, hi, lo);
    short8 b00 = frag_ld(Bs, lo, 0, hi, lo);
    short8 b01 = frag_ld(Bs, lo, 1, hi, lo);
    short8 b10 = frag_ld(Bs, 16 + lo, 0, hi, lo);
    short8 b11 = frag_ld(Bs, 16 + lo, 1, hi, lo);
    acc[0] = __builtin_amdgcn_mfma_f32_16x16x32_bf16(a0, b00, acc[0], 0, 0, 0);
    acc[0] = __builtin_amdgcn_mfma_f32_16x16x32_bf16(a1, b01, acc[0], 0, 0, 0);
    acc[1] = __builtin_amdgcn_mfma_f32_16x16x32_bf16(a0, b10, acc[1], 0, 0, 0);
    acc[1] = __builtin_amdgcn_mfma_f32_16x16x32_bf16(a1, b11, acc[1], 0, 0, 0);
    __syncthreads();
  }
  const int b = (int)(row0 >> 11);
#pragma unroll
  for (int ni = 0; ni < 2; ++ni) {
    const int col = ni * 16 + lo;
    const float g = gate[b * 4 + (col >> 3)];
#pragma unroll
    for (int j = 0; j < 4; ++j) {
      const size_t r = row0 + wave * 16 + hi * 4 + j;
      xa_w[r * (size_t)K_DIM + 4096 + col] = (short)f2b(acc[ni][j] * g);
    }
  }
}

// ---- K6: main GEMM, 8-phase-style schedule.
// LDS: 4 ring slots; slot s holds (A: 256 rows x 32 K) + (B: 256 rows x 32 K).
// Group g (K window [32g,32g+32)) lives in slot g&3. While consuming group g,
// stage group g+3 (phase 0: A-half, phase 1: B-half; 2 gloads each).
// One counted s_waitcnt vmcnt(8) per group, before its last barrier:
// outstanding then = groups g+2,g+3 (8 loads) -> group g+1 landed.
// Row = 64 B = 4 x 16B chunks; swizzle: phys chunk = logical ^ ((row>>1)&3)
// -> 2-way bank aliasing on ds_read_b128 (free), staged via pre-swizzled source.
__global__ __launch_bounds__(512, 2) void gemm_k(const short* __restrict__ A,
                                                 const short* __restrict__ B,
                                                 const float* __restrict__ bias,
                                                 float* __restrict__ C) {
  __shared__ short As[4][8192];   // 4 x 16 KB
  __shared__ short Bs[4][8192];   // 4 x 16 KB
  const int tid = threadIdx.x;
  const int lane = tid & 63;
  const int wave = tid >> 6;            // 0..7
  const int wm = wave >> 2;             // 0..1 -> rows wm*128..+128
  const int wn = wave & 3;              // 0..3 -> cols wn*64..+64
  const int lo = lane & 15, hi = lane >> 4;

  // T1: XCD swizzle (1024 blocks, 8 XCDs, bijective)
  const int wg = (blockIdx.x & 7) * 128 + (blockIdx.x >> 3);
  const int brow = wg >> 4;             // 0..63
  const int bcol = wg & 15;             // 0..15

  // staging: issue covers 128 rows (512 thr x 16 B); row = tid>>2 (+128 for
  // issue 1), phys chunk = tid&3, logical = phys ^ ((row>>1)&3) = ^(tid>>3)&3
  const int srow = tid >> 2;
  const int schunk = (tid & 3) ^ ((tid >> 3) & 3);
  const short* srcA = A + (size_t)(brow * 256 + srow) * K_DIM + schunk * 8;
  const short* srcB = B + (size_t)(bcol * 256 + srow) * K_DIM + schunk * 8;
  char* ldsA0 = (char*)(&As[0][0]) + wave * 1024;  // + slot*16384 + issue*8192
  char* ldsB0 = (char*)(&Bs[0][0]) + wave * 1024;

  // read swizzle: row's swizzle bits reduce to (lo>>1)&3 for all frag rows
  const int csw = (hi ^ ((lo >> 1) & 3)) * 8;
  const int aro = (wm * 128 + lo) * 32 + csw;      // + mi*512 (+2048 lower half)
  const int bro = (wn * 64 + lo) * 32 + csw;       // + ni*512

  float bz[4];
#pragma unroll
  for (int ni = 0; ni < 4; ++ni)
    bz[ni] = bias[bcol * 256 + wn * 64 + ni * 16 + lo];

  f32x4v acc[8][4] = {};

#define STAGE_A(koff, ss)                                                      \
  async_copy16(ldsA0 + (ss) * 16384, srcA + (koff));                           \
  async_copy16(ldsA0 + (ss) * 16384 + 8192, srcA + (size_t)128 * K_DIM + (koff));
#define STAGE_B(koff, ss)                                                      \
  async_copy16(ldsB0 + (ss) * 16384, srcB + (koff));                           \
  async_copy16(ldsB0 + (ss) * 16384 + 8192, srcB + (size_t)128 * K_DIM + (koff));

  // prologue: stage groups 0,1,2 (12 loads); wait until group 0 landed (8 left)
  STAGE_A(0, 0);  STAGE_B(0, 0);
  STAGE_A(32, 1); STAGE_B(32, 1);
  STAGE_A(64, 2); STAGE_B(64, 2);
  asm volatile("s_waitcnt vmcnt(8)" ::: "memory");
  __builtin_amdgcn_s_barrier();

  for (int g = 0; g < NGRP; ++g) {
    const int slot = g & 3;
    const int gs = (g <= NGRP - 4) ? (g + 3) : (g - 1);  // tail: re-stage dead slot
    const int ss = gs & 3;                               // == (g+3)&3 either way
    const size_t ko = (size_t)gs * 32;
    const short* Aslot = &As[0][0] + slot * 8192;
    const short* Bslot = &Bs[0][0] + slot * 8192;

    // ---- phase 0: frags A(mi0-3) + B(ni0-3); stage A(g+3); MFMA upper half
    short8 afr[4], bfr[4];
#pragma unroll
    for (int mi = 0; mi < 4; ++mi)
      afr[mi] = *(const short8*)(&Aslot[aro + mi * 512]);
#pragma unroll
    for (int ni = 0; ni < 4; ++ni)
      bfr[ni] = *(const short8*)(&Bslot[bro + ni * 512]);
    STAGE_A(ko, ss);
    __builtin_amdgcn_s_barrier();
    asm volatile("s_waitcnt lgkmcnt(0)" ::: "memory");
    __builtin_amdgcn_sched_barrier(0);
    __builtin_amdgcn_s_setprio(1);
#pragma unroll
    for (int mi = 0; mi < 4; ++mi)
#pragma unroll
      for (int ni = 0; ni < 4; ++ni)
        acc[mi][ni] = __builtin_amdgcn_mfma_f32_16x16x32_bf16(afr[mi], bfr[ni], acc[mi][ni], 0, 0, 0);
    __builtin_amdgcn_s_setprio(0);
    __builtin_amdgcn_s_barrier();

    // ---- phase 1: frags A(mi4-7); stage B(g+3); counted vmcnt; MFMA lower half
    short8 afr2[4];
#pragma unroll
    for (int mi = 0; mi < 4; ++mi)
      afr2[mi] = *(const short8*)(&Aslot[aro + 2048 + mi * 512]);
    STAGE_B(ko, ss);
    asm volatile("s_waitcnt vmcnt(8)" ::: "memory");   // groups g+2,g+3 in flight
    __builtin_amdgcn_s_barrier();
    asm volatile("s_waitcnt lgkmcnt(0)" ::: "memory");
    __builtin_amdgcn_sched_barrier(0);
    __builtin_amdgcn_s_setprio(1);
#pragma unroll
    for (int mi = 0; mi < 4; ++mi)
#pragma unroll
      for (int ni = 0; ni < 4; ++ni)
        acc[mi + 4][ni] = __builtin_amdgcn_mfma_f32_16x16x32_bf16(afr2[mi], bfr[ni], acc[mi + 4][ni], 0, 0, 0);
    __builtin_amdgcn_s_setprio(0);
    __builtin_amdgcn_s_barrier();
  }
  asm volatile("s_waitcnt vmcnt(0)" ::: "memory");

#pragma unroll
  for (int mi = 0; mi < 8; ++mi) {
#pragma unroll
    for (int ni = 0; ni < 4; ++ni) {
      const int r0 = brow * 256 + wm * 128 + mi * 16 + hi * 4;
      const int c0 = bcol * 256 + wn * 64 + ni * 16 + lo;
#pragma unroll
      for (int j = 0; j < 4; ++j)
        C[(size_t)(r0 + j) * N_DIM + c0] = acc[mi][ni][j] + bz[ni];
    }
  }
#undef STAGE_A
#undef STAGE_B
}

extern "C" void kernel_launch(void* const* d_in, const int* in_sizes, int n_in,
                              void* d_out, int out_size, void* d_ws, size_t ws_size,
                              hipStream_t stream) {
  const float* x      = (const float*)d_in[0];
  const float* scores = (const float*)d_in[1];
  const float* Wb     = (const float*)d_in[2];
  const float* bb     = (const float*)d_in[3];
  const float* gW     = (const float*)d_in[4];
  const float* Wr     = (const float*)d_in[5];
  const float* lA     = (const float*)d_in[6];
  const float* lB     = (const float*)d_in[7];
  const int*   midx   = (const int*)d_in[8];
  const int*   kk     = (const int*)d_in[9];
  float* out = (float*)d_out;

  char* ws = (char*)d_ws;
  short* xa    = (short*)ws;                                        // 136,314,880 B
  short* wa    = (short*)(ws + 136314880u);                         //  34,078,720 B
  float* gated = (float*)(ws + 136314880u + 34078720u);             //     131,072 B
  float* gate  = (float*)(ws + 136314880u + 34078720u + 131072u);   //         128 B
  short* lAb   = (short*)(ws + 136314880u + 34078720u + 131072u + 128u);  // 262,144 B

  cvt_x_k<<<33280, 256, 0, stream>>>(x, xa);
  cvt_w_k<<<8320, 256, 0, stream>>>(Wb, lB, wa);
  cvt_la_k<<<64, 256, 0, stream>>>(lA, lAb);
  gated_k<<<4096, 256, 0, stream>>>(x, gW, gated);
  gate_k<<<1, 64, 0, stream>>>(gated, Wr, scores, midx, kk, gate);
  lora_t_k<<<256, 256, 0, stream>>>(xa, lAb, gate, xa);
  gemm_k<<<1024, 512, 0, stream>>>(xa, wa, bb, out);
}

// Round 6
// 805.288 us; speedup vs baseline: 1.0959x; 1.0959x over previous
//
#include <hip/hip_runtime.h>
#include <hip/hip_bf16.h>

// DynaLoRALinear via K-augmented bf16 GEMM:
//   x_aug[row][0:4096]=bf16(x), [4096:4128]=gate*t, [4128:4160]=0
//   W_aug[o][0:4096]=bf16(W_base), [4096+e*8+r]=bf16(lora_B[e,o,r]), rest 0
//   out = x_aug @ W_aug^T + b_base   (M=16384, N=4096, K=4160)
// GEMM: 256x256 tile, 8 waves, ring-of-4 K=32 slots, balanced 2-region/group
// schedule: each barrier-delimited region holds {16 MFMA + frag reads + stage
// issues} so the compiler interleaves LDS and MFMA streams. Counted vmcnt(8),
// no sched_barrier / no explicit lgkm (R4 post-mortem), setprio, XCD swizzle.

typedef short short8 __attribute__((ext_vector_type(8)));
typedef float f32x4v __attribute__((ext_vector_type(4)));

#define M_DIM 16384
#define N_DIM 4096
#define K_DIM 4160   // 65 * 64 = 130 * 32
#define D_DIM 4096
#define NGRP 130     // 32-wide K groups

__device__ __forceinline__ unsigned short f2b(float f) {
  unsigned u = __builtin_bit_cast(unsigned, f);
  return (unsigned short)((u + 0x7FFFu + ((u >> 16) & 1u)) >> 16);  // RNE
}
__device__ __forceinline__ void async_copy16(void* lds, const void* g) {
  __builtin_amdgcn_global_load_lds(
      (const __attribute__((address_space(1))) void*)g,
      (__attribute__((address_space(3))) void*)lds, 16, 0, 0);
}
// 64-col (128 B-row) LDS tiles (xcvt kernel): phys 16B-slot p of row r holds
// logical l = p ^ (r&7); read logical l at p = l ^ (r&7).
__device__ __forceinline__ short8 frag_ld(const short* base, int row, int ks, int hi, int lo) {
  return *(const short8*)(&base[row * 64 + (((ks * 4 + hi) ^ (lo & 7)) * 8)]);
}

// ---- K2: W_base -> W_aug, pack lora_B into cols 4096..4127, zero rest
__global__ __launch_bounds__(256) void cvt_w_k(const float* __restrict__ Wb,
                                               const float* __restrict__ lB,
                                               short* __restrict__ wa) {
  size_t idx = (size_t)blockIdx.x * 256 + threadIdx.x;   // 4096*520
  size_t row = idx / 520;
  int cc = (int)(idx % 520);
  short8 o;
  if (cc < 512) {
    const float* src = Wb + row * (size_t)D_DIM + (size_t)cc * 8;
    float4 a = *(const float4*)(src);
    float4 b = *(const float4*)(src + 4);
    o[0] = (short)f2b(a.x); o[1] = (short)f2b(a.y);
    o[2] = (short)f2b(a.z); o[3] = (short)f2b(a.w);
    o[4] = (short)f2b(b.x); o[5] = (short)f2b(b.y);
    o[6] = (short)f2b(b.z); o[7] = (short)f2b(b.w);
  } else if (cc < 516) {
    int e = cc - 512;
    const float* src = lB + (size_t)e * (D_DIM * 8) + row * 8;
    float4 a = *(const float4*)(src);
    float4 b = *(const float4*)(src + 4);
    o[0] = (short)f2b(a.x); o[1] = (short)f2b(a.y);
    o[2] = (short)f2b(a.z); o[3] = (short)f2b(a.w);
    o[4] = (short)f2b(b.x); o[5] = (short)f2b(b.y);
    o[6] = (short)f2b(b.z); o[7] = (short)f2b(b.w);
  } else {
#pragma unroll
    for (int t = 0; t < 8; ++t) o[t] = 0;
  }
  *(short8*)(wa + row * (size_t)K_DIM + (size_t)cc * 8) = o;
}

// ---- K2b: lora_A (f32 [32][4096]) -> bf16
__global__ __launch_bounds__(256) void cvt_la_k(const float* __restrict__ lA,
                                                short* __restrict__ lAb) {
  size_t i = (size_t)blockIdx.x * 256 + threadIdx.x;
  const float* s = lA + i * 8;
  float4 a = *(const float4*)s;
  float4 b = *(const float4*)(s + 4);
  short8 o;
  o[0] = (short)f2b(a.x); o[1] = (short)f2b(a.y);
  o[2] = (short)f2b(a.z); o[3] = (short)f2b(a.w);
  o[4] = (short)f2b(b.x); o[5] = (short)f2b(b.y);
  o[6] = (short)f2b(b.z); o[7] = (short)f2b(b.w);
  *(short8*)(lAb + i * 8) = o;
}

// ---- K3: gated[b][j] = dot(x[b,L-1,:], gating_W[j,:]) (exact f32 path)
__global__ __launch_bounds__(256) void gated_k(const float* __restrict__ x,
                                               const float* __restrict__ gW,
                                               float* __restrict__ gated) {
  const int j = blockIdx.x;
  const int tid = threadIdx.x;
  float acc[8];
#pragma unroll
  for (int b = 0; b < 8; ++b) acc[b] = 0.f;
  const float* w = gW + (size_t)j * D_DIM;
  for (int i = tid * 4; i < D_DIM; i += 1024) {
    float4 wv = *(const float4*)(w + i);
#pragma unroll
    for (int b = 0; b < 8; ++b) {
      const float* p = x + ((size_t)b * 2048 + 2047) * D_DIM + i;
      float4 pv = *(const float4*)p;
      acc[b] += wv.x * pv.x + wv.y * pv.y + wv.z * pv.z + wv.w * pv.w;
    }
  }
  __shared__ float red[8][4];
  const int lane = tid & 63, wv_ = tid >> 6;
#pragma unroll
  for (int b = 0; b < 8; ++b) {
    float v = acc[b];
    v += __shfl_down(v, 32); v += __shfl_down(v, 16); v += __shfl_down(v, 8);
    v += __shfl_down(v, 4);  v += __shfl_down(v, 2);  v += __shfl_down(v, 1);
    if (lane == 0) red[b][wv_] = v;
  }
  __syncthreads();
  if (tid < 8)
    gated[(size_t)tid * D_DIM + j] = red[tid][0] + red[tid][1] + red[tid][2] + red[tid][3];
}

// ---- K4: logits -> softmax -> module_prob -> top-k gate (1 wave)
__global__ void gate_k(const float* __restrict__ gated, const float* __restrict__ Wr,
                       const float* __restrict__ scores, const int* __restrict__ midx_p,
                       const int* __restrict__ kp, float* __restrict__ gate) {
  const int lane = threadIdx.x;
  float acc[56];
#pragma unroll
  for (int t = 0; t < 56; ++t) acc[t] = 0.f;
  for (int i = lane * 4; i < D_DIM; i += 256) {
    float4 g[8]; float4 w[7];
#pragma unroll
    for (int b = 0; b < 8; ++b) g[b] = *(const float4*)(gated + (size_t)b * D_DIM + i);
#pragma unroll
    for (int m = 0; m < 7; ++m) w[m] = *(const float4*)(Wr + (size_t)m * D_DIM + i);
#pragma unroll
    for (int m = 0; m < 7; ++m)
#pragma unroll
      for (int b = 0; b < 8; ++b)
        acc[m * 8 + b] += w[m].x * g[b].x + w[m].y * g[b].y + w[m].z * g[b].z + w[m].w * g[b].w;
  }
  __shared__ float Ls[56];
#pragma unroll
  for (int t = 0; t < 56; ++t) {
    float v = acc[t];
    v += __shfl_xor(v, 1); v += __shfl_xor(v, 2); v += __shfl_xor(v, 4);
    v += __shfl_xor(v, 8); v += __shfl_xor(v, 16); v += __shfl_xor(v, 32);
    if (lane == t) Ls[t] = v;
  }
  __syncthreads();
  if (lane < 8) {
    const int b = lane;
    float mx = -1e30f;
    for (int m = 0; m < 7; ++m) mx = fmaxf(mx, Ls[m * 8 + b]);
    float s = 0.f;
    for (int m = 0; m < 7; ++m) s += expf(Ls[m * 8 + b] - mx);
    const int mi = midx_p[0];
    const float mp = expf(Ls[mi * 8 + b] - mx) / s;
    int kv = kp[0]; if (kv < 1) kv = 1;
    int klo = kv >> 1; if (klo < 1) klo = 1;
    float sc[4];
#pragma unroll
    for (int e = 0; e < 4; ++e) sc[e] = scores[b * 4 + e];
#pragma unroll
    for (int e = 0; e < 4; ++e) {
      int rank = 0;
#pragma unroll
      for (int e2 = 0; e2 < 4; ++e2)
        rank += (sc[e2] > sc[e] || (sc[e2] == sc[e] && e2 < e)) ? 1 : 0;
      float wv = (mp > 0.5f) ? ((rank < kv) ? 1.0f / (float)kv : 0.f)
                             : ((rank < klo) ? 1.0f / (float)klo : 0.f);
      gate[b * 4 + e] = wv;
    }
  }
}

// ---- K5 (fused): convert x->bf16 into xa[:,0:4096] AND compute
// t = x @ lora_A^T (per 64-row block, MFMA vs LDS-staged tiles), scale by
// gate -> xa[:,4096:4128]; zero xa[:,4128:4159]. Replaces cvt_x + lora_t
// (saves the 134 MB xa re-read).
__global__ __launch_bounds__(256) void xcvt_lora_k(const float* __restrict__ x,
                                                   const short* __restrict__ LAb,
                                                   const float* __restrict__ gate,
                                                   short* __restrict__ xa) {
  __shared__ short As[4096];   // 64 x 64 bf16, swizzled 16B slots
  __shared__ short Bs[2048];   // 32 x 64 bf16
  const int tid = threadIdx.x, lane = tid & 63, wave = tid >> 6;
  const int lo = lane & 15, hi = lane >> 4;
  const size_t row0 = (size_t)blockIdx.x * 64;
  const int xr = tid >> 2;              // local row 0..63
  const int xc = tid & 3;               // 16-col chunk 0..3
  const float* xsrc = x + (row0 + xr) * (size_t)D_DIM + xc * 16;
  short* xdst = xa + (row0 + xr) * (size_t)K_DIM + xc * 16;
  // B stage (async, pre-swizzled source): rows tid>>3 (0..31), phys slot tid&7
  const int bsr = tid >> 3;
  const int bslot = (tid & 7) ^ (bsr & 7);
  const short* gB = LAb + (size_t)bsr * D_DIM + bslot * 8;
  f32x4v acc[2] = {};

  float4 v0, v1, v2, v3;
  v0 = *(const float4*)(xsrc + 0);
  v1 = *(const float4*)(xsrc + 4);
  v2 = *(const float4*)(xsrc + 8);
  v3 = *(const float4*)(xsrc + 12);

  for (int t = 0; t < 64; ++t) {
    const int kt = t * 64;
    short8 o0, o1;
    o0[0] = (short)f2b(v0.x); o0[1] = (short)f2b(v0.y);
    o0[2] = (short)f2b(v0.z); o0[3] = (short)f2b(v0.w);
    o0[4] = (short)f2b(v1.x); o0[5] = (short)f2b(v1.y);
    o0[6] = (short)f2b(v1.z); o0[7] = (short)f2b(v1.w);
    o1[0] = (short)f2b(v2.x); o1[1] = (short)f2b(v2.y);
    o1[2] = (short)f2b(v2.z); o1[3] = (short)f2b(v2.w);
    o1[4] = (short)f2b(v3.x); o1[5] = (short)f2b(v3.y);
    o1[6] = (short)f2b(v3.z); o1[7] = (short)f2b(v3.w);
    // global write (cols kt + xc*16 .. +16)
    *(short8*)(xdst + kt) = o0;
    *(short8*)(xdst + kt + 8) = o1;
    // LDS write, swizzled: logical slots 2*xc, 2*xc+1 of row xr
    const int l0 = 2 * xc;
    *(short8*)(&As[xr * 64 + ((l0 ^ (xr & 7)) * 8)]) = o0;
    *(short8*)(&As[xr * 64 + (((l0 + 1) ^ (xr & 7)) * 8)]) = o1;
    // B tile for this kt
    async_copy16((char*)Bs + wave * 1024, gB + kt);
    __syncthreads();
    // prefetch next x chunk (overlaps MFMA below)
    if (t < 63) {
      v0 = *(const float4*)(xsrc + kt + 64);
      v1 = *(const float4*)(xsrc + kt + 68);
      v2 = *(const float4*)(xsrc + kt + 72);
      v3 = *(const float4*)(xsrc + kt + 76);
    }
    short8 a0 = frag_ld(As, wave * 16 + lo, 0, hi, lo);
    short8 a1 = frag_ld(As, wave * 16 + lo, 1, hi, lo);
    short8 b00 = frag_ld(Bs, lo, 0, hi, lo);
    short8 b01 = frag_ld(Bs, lo, 1, hi, lo);
    short8 b10 = frag_ld(Bs, 16 + lo, 0, hi, lo);
    short8 b11 = frag_ld(Bs, 16 + lo, 1, hi, lo);
    acc[0] = __builtin_amdgcn_mfma_f32_16x16x32_bf16(a0, b00, acc[0], 0, 0, 0);
    acc[0] = __builtin_amdgcn_mfma_f32_16x16x32_bf16(a1, b01, acc[0], 0, 0, 0);
    acc[1] = __builtin_amdgcn_mfma_f32_16x16x32_bf16(a0, b10, acc[1], 0, 0, 0);
    acc[1] = __builtin_amdgcn_mfma_f32_16x16x32_bf16(a1, b11, acc[1], 0, 0, 0);
    __syncthreads();
  }
  // zero pad cols 4128..4159
  {
    short8 z;
#pragma unroll
    for (int t = 0; t < 8; ++t) z[t] = 0;
    *(short8*)(xa + (row0 + xr) * (size_t)K_DIM + 4128 + xc * 8) = z;
  }
  // gate-scale t and write cols 4096..4127
  const int b = (int)(row0 >> 11);
#pragma unroll
  for (int ni = 0; ni < 2; ++ni) {
    const int col = ni * 16 + lo;
    const float g = gate[b * 4 + (col >> 3)];
#pragma unroll
    for (int j = 0; j < 4; ++j) {
      const size_t r = row0 + wave * 16 + hi * 4 + j;
      xa[r * (size_t)K_DIM + 4096 + col] = (short)f2b(acc[ni][j] * g);
    }
  }
}

// ---- K6: main GEMM. Ring-of-4 K=32 slots; per group two barrier-delimited
// regions, each containing one 16-MFMA cluster PLUS the next frag reads /
// stage issues (compiler interleaves LDS and MFMA streams). vmcnt(8)/group.
__global__ __launch_bounds__(512, 2) void gemm_k(const short* __restrict__ A,
                                                 const short* __restrict__ B,
                                                 const float* __restrict__ bias,
                                                 float* __restrict__ C) {
  __shared__ short As[4][8192];   // 4 x 16 KB (256 rows x 32 K)
  __shared__ short Bs[4][8192];
  const int tid = threadIdx.x;
  const int lane = tid & 63;
  const int wave = tid >> 6;            // 0..7
  const int wm = wave >> 2;             // 0..1 -> rows wm*128..+128
  const int wn = wave & 3;              // 0..3 -> cols wn*64..+64
  const int lo = lane & 15, hi = lane >> 4;

  // T1: XCD swizzle (1024 blocks, 8 XCDs, bijective)
  const int wg = (blockIdx.x & 7) * 128 + (blockIdx.x >> 3);
  const int brow = wg >> 4;             // 0..63
  const int bcol = wg & 15;             // 0..15

  // staging: 512 thr x 16 B covers 128 rows x 32 K; row = tid>>2, phys chunk
  // tid&3, logical = phys ^ ((row>>1)&3) = phys ^ ((tid>>3)&3)
  const int srow = tid >> 2;
  const int schunk = (tid & 3) ^ ((tid >> 3) & 3);
  const short* srcA = A + (size_t)(brow * 256 + srow) * K_DIM + schunk * 8;
  const short* srcB = B + (size_t)(bcol * 256 + srow) * K_DIM + schunk * 8;
  char* ldsA0 = (char*)(&As[0][0]) + wave * 1024;  // + slot*16384 + issue*8192
  char* ldsB0 = (char*)(&Bs[0][0]) + wave * 1024;

  // read swizzle: phys chunk = (hi ^ ((lo>>1)&3)), in shorts:
  const int csw = (hi ^ ((lo >> 1) & 3)) * 8;
  const int aro = (wm * 128 + lo) * 32 + csw;      // + mi*512 (+2048 lower half)
  const int bro = (wn * 64 + lo) * 32 + csw;       // + ni*512

  float bz[4];
#pragma unroll
  for (int ni = 0; ni < 4; ++ni)
    bz[ni] = bias[bcol * 256 + wn * 64 + ni * 16 + lo];

  f32x4v acc[8][4] = {};

#define STAGE_A(koff, ss)                                                      \
  async_copy16(ldsA0 + (ss) * 16384, srcA + (koff));                           \
  async_copy16(ldsA0 + (ss) * 16384 + 8192, srcA + (size_t)128 * K_DIM + (koff));
#define STAGE_B(koff, ss)                                                      \
  async_copy16(ldsB0 + (ss) * 16384, srcB + (koff));                           \
  async_copy16(ldsB0 + (ss) * 16384 + 8192, srcB + (size_t)128 * K_DIM + (koff));

  // prologue: stage groups 0,1,2 (12 loads); slot0 landed when <=8 remain
  STAGE_A(0, 0);  STAGE_B(0, 0);
  STAGE_A(32, 1); STAGE_B(32, 1);
  STAGE_A(64, 2); STAGE_B(64, 2);
  asm volatile("s_waitcnt vmcnt(8)" ::: "memory");
  __builtin_amdgcn_s_barrier();

#pragma unroll 4
  for (int g = 0; g < NGRP; ++g) {
    const int slot = g & 3;
    const int gs = (g <= NGRP - 4) ? (g + 3) : (g - 1);  // tail: dead re-stage
    const int ss = gs & 3;
    const size_t ko = (size_t)gs * 32;
    const short* Aslot = &As[0][0] + slot * 8192;
    const short* Bslot = &Bs[0][0] + slot * 8192;

    // ---- region A (follows bar2 of g-1; contains MFMA-low(g-1) from loop
    // rotation + these reads): frags for upper half + B
    short8 afr[4], bfr[4];
#pragma unroll
    for (int mi = 0; mi < 4; ++mi)
      afr[mi] = *(const short8*)(&Aslot[aro + mi * 512]);
#pragma unroll
    for (int ni = 0; ni < 4; ++ni)
      bfr[ni] = *(const short8*)(&Bslot[bro + ni * 512]);
    __builtin_amdgcn_s_barrier();   // bar1

    // ---- region B: MFMA-up || afr2 reads || stage(g+3) || vmcnt
    __builtin_amdgcn_s_setprio(1);
#pragma unroll
    for (int mi = 0; mi < 4; ++mi)
#pragma unroll
      for (int ni = 0; ni < 4; ++ni)
        acc[mi][ni] = __builtin_amdgcn_mfma_f32_16x16x32_bf16(afr[mi], bfr[ni], acc[mi][ni], 0, 0, 0);
    __builtin_amdgcn_s_setprio(0);
    short8 afr2[4];
#pragma unroll
    for (int mi = 0; mi < 4; ++mi)
      afr2[mi] = *(const short8*)(&Aslot[aro + 2048 + mi * 512]);
    STAGE_A(ko, ss);
    STAGE_B(ko, ss);
    asm volatile("s_waitcnt vmcnt(8)" ::: "memory");  // g+1 landed; g+2,g+3 fly
    __builtin_amdgcn_s_barrier();   // bar2

    // ---- MFMA-low (start of next region A)
    __builtin_amdgcn_s_setprio(1);
#pragma unroll
    for (int mi = 0; mi < 4; ++mi)
#pragma unroll
      for (int ni = 0; ni < 4; ++ni)
        acc[mi + 4][ni] = __builtin_amdgcn_mfma_f32_16x16x32_bf16(afr2[mi], bfr[ni], acc[mi + 4][ni], 0, 0, 0);
    __builtin_amdgcn_s_setprio(0);
  }
  asm volatile("s_waitcnt vmcnt(0)" ::: "memory");

#pragma unroll
  for (int mi = 0; mi < 8; ++mi) {
#pragma unroll
    for (int ni = 0; ni < 4; ++ni) {
      const int r0 = brow * 256 + wm * 128 + mi * 16 + hi * 4;
      const int c0 = bcol * 256 + wn * 64 + ni * 16 + lo;
#pragma unroll
      for (int j = 0; j < 4; ++j)
        C[(size_t)(r0 + j) * N_DIM + c0] = acc[mi][ni][j] + bz[ni];
    }
  }
#undef STAGE_A
#undef STAGE_B
}

extern "C" void kernel_launch(void* const* d_in, const int* in_sizes, int n_in,
                              void* d_out, int out_size, void* d_ws, size_t ws_size,
                              hipStream_t stream) {
  const float* x      = (const float*)d_in[0];
  const float* scores = (const float*)d_in[1];
  const float* Wb     = (const float*)d_in[2];
  const float* bb     = (const float*)d_in[3];
  const float* gW     = (const float*)d_in[4];
  const float* Wr     = (const float*)d_in[5];
  const float* lA     = (const float*)d_in[6];
  const float* lB     = (const float*)d_in[7];
  const int*   midx   = (const int*)d_in[8];
  const int*   kk     = (const int*)d_in[9];
  float* out = (float*)d_out;

  char* ws = (char*)d_ws;
  short* xa    = (short*)ws;                                        // 136,314,880 B
  short* wa    = (short*)(ws + 136314880u);                         //  34,078,720 B
  float* gated = (float*)(ws + 136314880u + 34078720u);             //     131,072 B
  float* gate  = (float*)(ws + 136314880u + 34078720u + 131072u);   //         128 B
  short* lAb   = (short*)(ws + 136314880u + 34078720u + 131072u + 128u);  // 262,144 B

  cvt_w_k<<<8320, 256, 0, stream>>>(Wb, lB, wa);
  cvt_la_k<<<64, 256, 0, stream>>>(lA, lAb);
  gated_k<<<4096, 256, 0, stream>>>(x, gW, gated);
  gate_k<<<1, 64, 0, stream>>>(gated, Wr, scores, midx, kk, gate);
  xcvt_lora_k<<<256, 256, 0, stream>>>(x, lAb, gate, xa);
  gemm_k<<<1024, 512, 0, stream>>>(xa, wa, bb, out);
}

// Round 7
// 720.922 us; speedup vs baseline: 1.2241x; 1.1170x over previous
//
#include <hip/hip_runtime.h>
#include <hip/hip_bf16.h>

// DynaLoRALinear via K-augmented bf16 GEMM:
//   x_aug[row][0:4096]=bf16(x), [4096:4128]=gate*t, [4128:4160]=0
//   W_aug[o][0:4096]=bf16(W_base), [4096+e*8+r]=bf16(lora_B[e,o,r]), rest 0
//   out = x_aug @ W_aug^T + b_base   (M=16384, N=4096, K=4160)
// GEMM R7: 256x256 tile, 8 waves, ring-of-4 K=32 slots, ONE barrier + ONE
// counted vmcnt(8) per group (130 total, half of R6's 260): whole group
// {12 ds_read_b128 || 32 MFMA || 4 global_load_lds} is a single
// compiler-scheduled region. Hazard-checked: stage(g+3) vs reads(g) needs
// 2-group skew; 1 bar/group bounds skew to 1 group. T2 swizzle, T5 setprio,
// T1 XCD swizzle. Side kernels: R3 split restored (R6 fusion was -33us).

typedef short short8 __attribute__((ext_vector_type(8)));
typedef float f32x4v __attribute__((ext_vector_type(4)));

#define M_DIM 16384
#define N_DIM 4096
#define K_DIM 4160   // 65 * 64 = 130 * 32
#define D_DIM 4096
#define NGRP 130     // 32-wide K groups

__device__ __forceinline__ unsigned short f2b(float f) {
  unsigned u = __builtin_bit_cast(unsigned, f);
  return (unsigned short)((u + 0x7FFFu + ((u >> 16) & 1u)) >> 16);  // RNE
}
__device__ __forceinline__ void async_copy16(void* lds, const void* g) {
  __builtin_amdgcn_global_load_lds(
      (const __attribute__((address_space(1))) void*)g,
      (__attribute__((address_space(3))) void*)lds, 16, 0, 0);
}
// 64-col (128 B-row) LDS tiles (lora_t kernel): phys 16B-slot p of row r holds
// logical l = p ^ (r&7); read logical l at p = l ^ (r&7).
__device__ __forceinline__ short8 frag_ld(const short* base, int row, int ks, int hi, int lo) {
  return *(const short8*)(&base[row * 64 + (((ks * 4 + hi) ^ (lo & 7)) * 8)]);
}

// ---- K1: x (f32) -> x_aug (bf16, stride 4160), zero cols 4096..4159
__global__ __launch_bounds__(256) void cvt_x_k(const float* __restrict__ x,
                                               short* __restrict__ xa) {
  size_t idx = (size_t)blockIdx.x * 256 + threadIdx.x;   // 16384*520
  size_t row = idx / 520;
  int cc = (int)(idx % 520);
  short8 o;
  if (cc < 512) {
    const float* src = x + row * (size_t)D_DIM + (size_t)cc * 8;
    float4 a = *(const float4*)(src);
    float4 b = *(const float4*)(src + 4);
    o[0] = (short)f2b(a.x); o[1] = (short)f2b(a.y);
    o[2] = (short)f2b(a.z); o[3] = (short)f2b(a.w);
    o[4] = (short)f2b(b.x); o[5] = (short)f2b(b.y);
    o[6] = (short)f2b(b.z); o[7] = (short)f2b(b.w);
  } else {
#pragma unroll
    for (int t = 0; t < 8; ++t) o[t] = 0;
  }
  *(short8*)(xa + row * (size_t)K_DIM + (size_t)cc * 8) = o;
}

// ---- K2: W_base -> W_aug, pack lora_B into cols 4096..4127, zero rest
__global__ __launch_bounds__(256) void cvt_w_k(const float* __restrict__ Wb,
                                               const float* __restrict__ lB,
                                               short* __restrict__ wa) {
  size_t idx = (size_t)blockIdx.x * 256 + threadIdx.x;   // 4096*520
  size_t row = idx / 520;
  int cc = (int)(idx % 520);
  short8 o;
  if (cc < 512) {
    const float* src = Wb + row * (size_t)D_DIM + (size_t)cc * 8;
    float4 a = *(const float4*)(src);
    float4 b = *(const float4*)(src + 4);
    o[0] = (short)f2b(a.x); o[1] = (short)f2b(a.y);
    o[2] = (short)f2b(a.z); o[3] = (short)f2b(a.w);
    o[4] = (short)f2b(b.x); o[5] = (short)f2b(b.y);
    o[6] = (short)f2b(b.z); o[7] = (short)f2b(b.w);
  } else if (cc < 516) {
    int e = cc - 512;
    const float* src = lB + (size_t)e * (D_DIM * 8) + row * 8;
    float4 a = *(const float4*)(src);
    float4 b = *(const float4*)(src + 4);
    o[0] = (short)f2b(a.x); o[1] = (short)f2b(a.y);
    o[2] = (short)f2b(a.z); o[3] = (short)f2b(a.w);
    o[4] = (short)f2b(b.x); o[5] = (short)f2b(b.y);
    o[6] = (short)f2b(b.z); o[7] = (short)f2b(b.w);
  } else {
#pragma unroll
    for (int t = 0; t < 8; ++t) o[t] = 0;
  }
  *(short8*)(wa + row * (size_t)K_DIM + (size_t)cc * 8) = o;
}

// ---- K2b: lora_A (f32 [32][4096]) -> bf16
__global__ __launch_bounds__(256) void cvt_la_k(const float* __restrict__ lA,
                                                short* __restrict__ lAb) {
  size_t i = (size_t)blockIdx.x * 256 + threadIdx.x;
  const float* s = lA + i * 8;
  float4 a = *(const float4*)s;
  float4 b = *(const float4*)(s + 4);
  short8 o;
  o[0] = (short)f2b(a.x); o[1] = (short)f2b(a.y);
  o[2] = (short)f2b(a.z); o[3] = (short)f2b(a.w);
  o[4] = (short)f2b(b.x); o[5] = (short)f2b(b.y);
  o[6] = (short)f2b(b.z); o[7] = (short)f2b(b.w);
  *(short8*)(lAb + i * 8) = o;
}

// ---- K3: gated[b][j] = dot(x[b,L-1,:], gating_W[j,:]) (exact f32 path)
__global__ __launch_bounds__(256) void gated_k(const float* __restrict__ x,
                                               const float* __restrict__ gW,
                                               float* __restrict__ gated) {
  const int j = blockIdx.x;
  const int tid = threadIdx.x;
  float acc[8];
#pragma unroll
  for (int b = 0; b < 8; ++b) acc[b] = 0.f;
  const float* w = gW + (size_t)j * D_DIM;
  for (int i = tid * 4; i < D_DIM; i += 1024) {
    float4 wv = *(const float4*)(w + i);
#pragma unroll
    for (int b = 0; b < 8; ++b) {
      const float* p = x + ((size_t)b * 2048 + 2047) * D_DIM + i;
      float4 pv = *(const float4*)p;
      acc[b] += wv.x * pv.x + wv.y * pv.y + wv.z * pv.z + wv.w * pv.w;
    }
  }
  __shared__ float red[8][4];
  const int lane = tid & 63, wv_ = tid >> 6;
#pragma unroll
  for (int b = 0; b < 8; ++b) {
    float v = acc[b];
    v += __shfl_down(v, 32); v += __shfl_down(v, 16); v += __shfl_down(v, 8);
    v += __shfl_down(v, 4);  v += __shfl_down(v, 2);  v += __shfl_down(v, 1);
    if (lane == 0) red[b][wv_] = v;
  }
  __syncthreads();
  if (tid < 8)
    gated[(size_t)tid * D_DIM + j] = red[tid][0] + red[tid][1] + red[tid][2] + red[tid][3];
}

// ---- K4: logits -> softmax -> module_prob -> top-k gate (1 wave)
__global__ void gate_k(const float* __restrict__ gated, const float* __restrict__ Wr,
                       const float* __restrict__ scores, const int* __restrict__ midx_p,
                       const int* __restrict__ kp, float* __restrict__ gate) {
  const int lane = threadIdx.x;
  float acc[56];
#pragma unroll
  for (int t = 0; t < 56; ++t) acc[t] = 0.f;
  for (int i = lane * 4; i < D_DIM; i += 256) {
    float4 g[8]; float4 w[7];
#pragma unroll
    for (int b = 0; b < 8; ++b) g[b] = *(const float4*)(gated + (size_t)b * D_DIM + i);
#pragma unroll
    for (int m = 0; m < 7; ++m) w[m] = *(const float4*)(Wr + (size_t)m * D_DIM + i);
#pragma unroll
    for (int m = 0; m < 7; ++m)
#pragma unroll
      for (int b = 0; b < 8; ++b)
        acc[m * 8 + b] += w[m].x * g[b].x + w[m].y * g[b].y + w[m].z * g[b].z + w[m].w * g[b].w;
  }
  __shared__ float Ls[56];
#pragma unroll
  for (int t = 0; t < 56; ++t) {
    float v = acc[t];
    v += __shfl_xor(v, 1); v += __shfl_xor(v, 2); v += __shfl_xor(v, 4);
    v += __shfl_xor(v, 8); v += __shfl_xor(v, 16); v += __shfl_xor(v, 32);
    if (lane == t) Ls[t] = v;
  }
  __syncthreads();
  if (lane < 8) {
    const int b = lane;
    float mx = -1e30f;
    for (int m = 0; m < 7; ++m) mx = fmaxf(mx, Ls[m * 8 + b]);
    float s = 0.f;
    for (int m = 0; m < 7; ++m) s += expf(Ls[m * 8 + b] - mx);
    const int mi = midx_p[0];
    const float mp = expf(Ls[mi * 8 + b] - mx) / s;
    int kv = kp[0]; if (kv < 1) kv = 1;
    int klo = kv >> 1; if (klo < 1) klo = 1;
    float sc[4];
#pragma unroll
    for (int e = 0; e < 4; ++e) sc[e] = scores[b * 4 + e];
#pragma unroll
    for (int e = 0; e < 4; ++e) {
      int rank = 0;
#pragma unroll
      for (int e2 = 0; e2 < 4; ++e2)
        rank += (sc[e2] > sc[e] || (sc[e2] == sc[e] && e2 < e)) ? 1 : 0;
      float wv = (mp > 0.5f) ? ((rank < kv) ? 1.0f / (float)kv : 0.f)
                             : ((rank < klo) ? 1.0f / (float)klo : 0.f);
      gate[b * 4 + e] = wv;
    }
  }
}

// ---- K5: LoRA-A projection as MFMA GEMM: t = xa[:, :4096] @ lAb^T (N=32),
// scaled by gate, written bf16 into xa cols 4096..4127. (R3 version, proven.)
__global__ __launch_bounds__(256) void lora_t_k(const short* __restrict__ XA,
                                                const short* __restrict__ LAb,
                                                const float* __restrict__ gate,
                                                short* __restrict__ xa_w) {
  __shared__ short As[4096];   // 64 x 64 bf16
  __shared__ short Bs[2048];   // 32 x 64 bf16
  const int tid = threadIdx.x, lane = tid & 63, wave = tid >> 6;
  const int lo = lane & 15, hi = lane >> 4;
  const size_t row0 = (size_t)blockIdx.x * 64;
  const int srow = tid >> 3;
  const int slot = (tid & 7) ^ (srow & 7);
  const short* gA = XA + (row0 + srow) * (size_t)K_DIM + slot * 8;
  const short* gB = LAb + (size_t)srow * D_DIM + slot * 8;
  f32x4v acc[2] = {};

  for (int t = 0; t < 64; ++t) {
    const int kt = t * 64;
    char* la = (char*)As + wave * 1024;
    char* lb = (char*)Bs + wave * 1024;
    async_copy16(la, gA + kt);
    async_copy16(la + 4096, gA + (size_t)32 * K_DIM + kt);
    async_copy16(lb, gB + kt);
    __syncthreads();
    short8 a0 = frag_ld(As, wave * 16 + lo, 0, hi, lo);
    short8 a1 = frag_ld(As, wave * 16 + lo, 1, hi, lo);
    short8 b00 = frag_ld(Bs, lo, 0, hi, lo);
    short8 b01 = frag_ld(Bs, lo, 1, hi, lo);
    short8 b10 = frag_ld(Bs, 16 + lo, 0, hi, lo);
    short8 b11 = frag_ld(Bs, 16 + lo, 1, hi, lo);
    acc[0] = __builtin_amdgcn_mfma_f32_16x16x32_bf16(a0, b00, acc[0], 0, 0, 0);
    acc[0] = __builtin_amdgcn_mfma_f32_16x16x32_bf16(a1, b01, acc[0], 0, 0, 0);
    acc[1] = __builtin_amdgcn_mfma_f32_16x16x32_bf16(a0, b10, acc[1], 0, 0, 0);
    acc[1] = __builtin_amdgcn_mfma_f32_16x16x32_bf16(a1, b11, acc[1], 0, 0, 0);
    __syncthreads();
  }
  const int b = (int)(row0 >> 11);
#pragma unroll
  for (int ni = 0; ni < 2; ++ni) {
    const int col = ni * 16 + lo;
    const float g = gate[b * 4 + (col >> 3)];
#pragma unroll
    for (int j = 0; j < 4; ++j) {
      const size_t r = row0 + wave * 16 + hi * 4 + j;
      xa_w[r * (size_t)K_DIM + 4096 + col] = (short)f2b(acc[ni][j] * g);
    }
  }
}

// ---- K6: main GEMM. Ring-of-4 K=32 slots; ONE barrier + ONE vmcnt(8) per
// group; whole group is a single scheduling region. Stage(g+3) issued between
// the two 16-MFMA setprio clusters.
__global__ __launch_bounds__(512, 2) void gemm_k(const short* __restrict__ A,
                                                 const short* __restrict__ B,
                                                 const float* __restrict__ bias,
                                                 float* __restrict__ C) {
  __shared__ short As[4][8192];   // 4 x 16 KB (256 rows x 32 K)
  __shared__ short Bs[4][8192];
  const int tid = threadIdx.x;
  const int lane = tid & 63;
  const int wave = tid >> 6;            // 0..7
  const int wm = wave >> 2;             // 0..1 -> rows wm*128..+128
  const int wn = wave & 3;              // 0..3 -> cols wn*64..+64
  const int lo = lane & 15, hi = lane >> 4;

  // T1: XCD swizzle (1024 blocks, 8 XCDs, bijective)
  const int wg = (blockIdx.x & 7) * 128 + (blockIdx.x >> 3);
  const int brow = wg >> 4;             // 0..63
  const int bcol = wg & 15;             // 0..15

  // staging: 512 thr x 16 B covers 128 rows x 32 K; row = tid>>2, phys chunk
  // tid&3, logical = phys ^ ((row>>1)&3) = phys ^ ((tid>>3)&3)
  const int srow = tid >> 2;
  const int schunk = (tid & 3) ^ ((tid >> 3) & 3);
  const short* srcA = A + (size_t)(brow * 256 + srow) * K_DIM + schunk * 8;
  const short* srcB = B + (size_t)(bcol * 256 + srow) * K_DIM + schunk * 8;
  char* ldsA0 = (char*)(&As[0][0]) + wave * 1024;  // + slot*16384 + issue*8192
  char* ldsB0 = (char*)(&Bs[0][0]) + wave * 1024;

  // read swizzle: phys chunk = (hi ^ ((lo>>1)&3)), in shorts:
  const int csw = (hi ^ ((lo >> 1) & 3)) * 8;
  const int aro = (wm * 128 + lo) * 32 + csw;      // + mi*512 (+2048 lower half)
  const int bro = (wn * 64 + lo) * 32 + csw;       // + ni*512

  float bz[4];
#pragma unroll
  for (int ni = 0; ni < 4; ++ni)
    bz[ni] = bias[bcol * 256 + wn * 64 + ni * 16 + lo];

  f32x4v acc[8][4] = {};

#define STAGE_A(koff, ss)                                                      \
  async_copy16(ldsA0 + (ss) * 16384, srcA + (koff));                           \
  async_copy16(ldsA0 + (ss) * 16384 + 8192, srcA + (size_t)128 * K_DIM + (koff));
#define STAGE_B(koff, ss)                                                      \
  async_copy16(ldsB0 + (ss) * 16384, srcB + (koff));                           \
  async_copy16(ldsB0 + (ss) * 16384 + 8192, srcB + (size_t)128 * K_DIM + (koff));

  // prologue: stage groups 0,1,2 (12 loads/wave); slot0 landed when <=8 remain
  STAGE_A(0, 0);  STAGE_B(0, 0);
  STAGE_A(32, 1); STAGE_B(32, 1);
  STAGE_A(64, 2); STAGE_B(64, 2);
  asm volatile("s_waitcnt vmcnt(8)" ::: "memory");
  __builtin_amdgcn_s_barrier();

#pragma unroll 4
  for (int g = 0; g < NGRP; ++g) {
    const int slot = g & 3;
    const int gs = (g <= NGRP - 4) ? (g + 3) : (g - 1);  // tail: dead re-stage
    const int ss = gs & 3;
    const size_t ko = (size_t)gs * 32;
    const short* Aslot = &As[0][0] + slot * 8192;
    const short* Bslot = &Bs[0][0] + slot * 8192;

    // one region per group: 12 ds_read_b128 + 32 MFMA + 4 gloads + vmcnt + bar
    short8 afr[4], afr2[4], bfr[4];
#pragma unroll
    for (int mi = 0; mi < 4; ++mi)
      afr[mi] = *(const short8*)(&Aslot[aro + mi * 512]);
#pragma unroll
    for (int ni = 0; ni < 4; ++ni)
      bfr[ni] = *(const short8*)(&Bslot[bro + ni * 512]);
#pragma unroll
    for (int mi = 0; mi < 4; ++mi)
      afr2[mi] = *(const short8*)(&Aslot[aro + 2048 + mi * 512]);

    __builtin_amdgcn_s_setprio(1);
#pragma unroll
    for (int mi = 0; mi < 4; ++mi)
#pragma unroll
      for (int ni = 0; ni < 4; ++ni)
        acc[mi][ni] = __builtin_amdgcn_mfma_f32_16x16x32_bf16(afr[mi], bfr[ni], acc[mi][ni], 0, 0, 0);
    __builtin_amdgcn_s_setprio(0);

    STAGE_A(ko, ss);
    STAGE_B(ko, ss);

    __builtin_amdgcn_s_setprio(1);
#pragma unroll
    for (int mi = 0; mi < 4; ++mi)
#pragma unroll
      for (int ni = 0; ni < 4; ++ni)
        acc[mi + 4][ni] = __builtin_amdgcn_mfma_f32_16x16x32_bf16(afr2[mi], bfr[ni], acc[mi + 4][ni], 0, 0, 0);
    __builtin_amdgcn_s_setprio(0);

    asm volatile("s_waitcnt vmcnt(8)" ::: "memory");  // slot g+1 landed; g+2,g+3 fly
    __builtin_amdgcn_s_barrier();
  }

#pragma unroll
  for (int mi = 0; mi < 8; ++mi) {
#pragma unroll
    for (int ni = 0; ni < 4; ++ni) {
      const int r0 = brow * 256 + wm * 128 + mi * 16 + hi * 4;
      const int c0 = bcol * 256 + wn * 64 + ni * 16 + lo;
#pragma unroll
      for (int j = 0; j < 4; ++j)
        C[(size_t)(r0 + j) * N_DIM + c0] = acc[mi][ni][j] + bz[ni];
    }
  }
#undef STAGE_A
#undef STAGE_B
}

extern "C" void kernel_launch(void* const* d_in, const int* in_sizes, int n_in,
                              void* d_out, int out_size, void* d_ws, size_t ws_size,
                              hipStream_t stream) {
  const float* x      = (const float*)d_in[0];
  const float* scores = (const float*)d_in[1];
  const float* Wb     = (const float*)d_in[2];
  const float* bb     = (const float*)d_in[3];
  const float* gW     = (const float*)d_in[4];
  const float* Wr     = (const float*)d_in[5];
  const float* lA     = (const float*)d_in[6];
  const float* lB     = (const float*)d_in[7];
  const int*   midx   = (const int*)d_in[8];
  const int*   kk     = (const int*)d_in[9];
  float* out = (float*)d_out;

  char* ws = (char*)d_ws;
  short* xa    = (short*)ws;                                        // 136,314,880 B
  short* wa    = (short*)(ws + 136314880u);                         //  34,078,720 B
  float* gated = (float*)(ws + 136314880u + 34078720u);             //     131,072 B
  float* gate  = (float*)(ws + 136314880u + 34078720u + 131072u);   //         128 B
  short* lAb   = (short*)(ws + 136314880u + 34078720u + 131072u + 128u);  // 262,144 B

  cvt_x_k<<<33280, 256, 0, stream>>>(x, xa);
  cvt_w_k<<<8320, 256, 0, stream>>>(Wb, lB, wa);
  cvt_la_k<<<64, 256, 0, stream>>>(lA, lAb);
  gated_k<<<4096, 256, 0, stream>>>(x, gW, gated);
  gate_k<<<1, 64, 0, stream>>>(gated, Wr, scores, midx, kk, gate);
  lora_t_k<<<256, 256, 0, stream>>>(xa, lAb, gate, xa);
  gemm_k<<<1024, 512, 0, stream>>>(xa, wa, bb, out);
}

// Round 8
// 705.924 us; speedup vs baseline: 1.2501x; 1.0212x over previous
//
#include <hip/hip_runtime.h>
#include <hip/hip_bf16.h>

// DynaLoRALinear via K-augmented bf16 GEMM:
//   x_aug[row][0:4096]=bf16(x), [4096:4128]=gate*t, [4128:4160]=0
//   W_aug[o][0:4096]=bf16(W_base), [4096+e*8+r]=bf16(lora_B[e,o,r]), rest 0
//   out = x_aug @ W_aug^T + b_base   (M=16384, N=4096, K=4160)
// GEMM R8: 256x256 tile, 8 waves, ring-of-5 K=32 slots (160 KB LDS), barrier
// every 2 groups (65 barriers): each region = {24 ds_read || 64 MFMA || 8
// gloads} -> compiler auto-pipelines group 2p+1 reads into group 2p MFMAs.
// vmcnt(4) per pair (stage(2p+3) landed, 2p+4 in flight). Safety: S=5 >= d+B
// = 3+2; read slots {2p,2p+1}%5 disjoint from write slots {2p+3,2p+4}%5.

typedef short short8 __attribute__((ext_vector_type(8)));
typedef float f32x4v __attribute__((ext_vector_type(4)));

#define M_DIM 16384
#define N_DIM 4096
#define K_DIM 4160   // 65 * 64 = 130 * 32
#define D_DIM 4096
#define NGRP 130     // 32-wide K groups

__device__ __forceinline__ unsigned short f2b(float f) {
  unsigned u = __builtin_bit_cast(unsigned, f);
  return (unsigned short)((u + 0x7FFFu + ((u >> 16) & 1u)) >> 16);  // RNE
}
__device__ __forceinline__ void async_copy16(void* lds, const void* g) {
  __builtin_amdgcn_global_load_lds(
      (const __attribute__((address_space(1))) void*)g,
      (__attribute__((address_space(3))) void*)lds, 16, 0, 0);
}
// 64-col (128 B-row) LDS tiles (lora_t kernel): phys 16B-slot p of row r holds
// logical l = p ^ (r&7); read logical l at p = l ^ (r&7).
__device__ __forceinline__ short8 frag_ld(const short* base, int row, int ks, int hi, int lo) {
  return *(const short8*)(&base[row * 64 + (((ks * 4 + hi) ^ (lo & 7)) * 8)]);
}

// ---- K1: x (f32) -> x_aug (bf16, stride 4160), zero cols 4096..4159
__global__ __launch_bounds__(256) void cvt_x_k(const float* __restrict__ x,
                                               short* __restrict__ xa) {
  size_t idx = (size_t)blockIdx.x * 256 + threadIdx.x;   // 16384*520
  size_t row = idx / 520;
  int cc = (int)(idx % 520);
  short8 o;
  if (cc < 512) {
    const float* src = x + row * (size_t)D_DIM + (size_t)cc * 8;
    float4 a = *(const float4*)(src);
    float4 b = *(const float4*)(src + 4);
    o[0] = (short)f2b(a.x); o[1] = (short)f2b(a.y);
    o[2] = (short)f2b(a.z); o[3] = (short)f2b(a.w);
    o[4] = (short)f2b(b.x); o[5] = (short)f2b(b.y);
    o[6] = (short)f2b(b.z); o[7] = (short)f2b(b.w);
  } else {
#pragma unroll
    for (int t = 0; t < 8; ++t) o[t] = 0;
  }
  *(short8*)(xa + row * (size_t)K_DIM + (size_t)cc * 8) = o;
}

// ---- K2: W_base -> W_aug, pack lora_B into cols 4096..4127, zero rest
__global__ __launch_bounds__(256) void cvt_w_k(const float* __restrict__ Wb,
                                               const float* __restrict__ lB,
                                               short* __restrict__ wa) {
  size_t idx = (size_t)blockIdx.x * 256 + threadIdx.x;   // 4096*520
  size_t row = idx / 520;
  int cc = (int)(idx % 520);
  short8 o;
  if (cc < 512) {
    const float* src = Wb + row * (size_t)D_DIM + (size_t)cc * 8;
    float4 a = *(const float4*)(src);
    float4 b = *(const float4*)(src + 4);
    o[0] = (short)f2b(a.x); o[1] = (short)f2b(a.y);
    o[2] = (short)f2b(a.z); o[3] = (short)f2b(a.w);
    o[4] = (short)f2b(b.x); o[5] = (short)f2b(b.y);
    o[6] = (short)f2b(b.z); o[7] = (short)f2b(b.w);
  } else if (cc < 516) {
    int e = cc - 512;
    const float* src = lB + (size_t)e * (D_DIM * 8) + row * 8;
    float4 a = *(const float4*)(src);
    float4 b = *(const float4*)(src + 4);
    o[0] = (short)f2b(a.x); o[1] = (short)f2b(a.y);
    o[2] = (short)f2b(a.z); o[3] = (short)f2b(a.w);
    o[4] = (short)f2b(b.x); o[5] = (short)f2b(b.y);
    o[6] = (short)f2b(b.z); o[7] = (short)f2b(b.w);
  } else {
#pragma unroll
    for (int t = 0; t < 8; ++t) o[t] = 0;
  }
  *(short8*)(wa + row * (size_t)K_DIM + (size_t)cc * 8) = o;
}

// ---- K2b: lora_A (f32 [32][4096]) -> bf16
__global__ __launch_bounds__(256) void cvt_la_k(const float* __restrict__ lA,
                                                short* __restrict__ lAb) {
  size_t i = (size_t)blockIdx.x * 256 + threadIdx.x;
  const float* s = lA + i * 8;
  float4 a = *(const float4*)s;
  float4 b = *(const float4*)(s + 4);
  short8 o;
  o[0] = (short)f2b(a.x); o[1] = (short)f2b(a.y);
  o[2] = (short)f2b(a.z); o[3] = (short)f2b(a.w);
  o[4] = (short)f2b(b.x); o[5] = (short)f2b(b.y);
  o[6] = (short)f2b(b.z); o[7] = (short)f2b(b.w);
  *(short8*)(lAb + i * 8) = o;
}

// ---- K3: gated[b][j] = dot(x[b,L-1,:], gating_W[j,:]) (exact f32 path)
__global__ __launch_bounds__(256) void gated_k(const float* __restrict__ x,
                                               const float* __restrict__ gW,
                                               float* __restrict__ gated) {
  const int j = blockIdx.x;
  const int tid = threadIdx.x;
  float acc[8];
#pragma unroll
  for (int b = 0; b < 8; ++b) acc[b] = 0.f;
  const float* w = gW + (size_t)j * D_DIM;
  for (int i = tid * 4; i < D_DIM; i += 1024) {
    float4 wv = *(const float4*)(w + i);
#pragma unroll
    for (int b = 0; b < 8; ++b) {
      const float* p = x + ((size_t)b * 2048 + 2047) * D_DIM + i;
      float4 pv = *(const float4*)p;
      acc[b] += wv.x * pv.x + wv.y * pv.y + wv.z * pv.z + wv.w * pv.w;
    }
  }
  __shared__ float red[8][4];
  const int lane = tid & 63, wv_ = tid >> 6;
#pragma unroll
  for (int b = 0; b < 8; ++b) {
    float v = acc[b];
    v += __shfl_down(v, 32); v += __shfl_down(v, 16); v += __shfl_down(v, 8);
    v += __shfl_down(v, 4);  v += __shfl_down(v, 2);  v += __shfl_down(v, 1);
    if (lane == 0) red[b][wv_] = v;
  }
  __syncthreads();
  if (tid < 8)
    gated[(size_t)tid * D_DIM + j] = red[tid][0] + red[tid][1] + red[tid][2] + red[tid][3];
}

// ---- K4: logits -> softmax -> module_prob -> top-k gate (1 wave)
__global__ void gate_k(const float* __restrict__ gated, const float* __restrict__ Wr,
                       const float* __restrict__ scores, const int* __restrict__ midx_p,
                       const int* __restrict__ kp, float* __restrict__ gate) {
  const int lane = threadIdx.x;
  float acc[56];
#pragma unroll
  for (int t = 0; t < 56; ++t) acc[t] = 0.f;
  for (int i = lane * 4; i < D_DIM; i += 256) {
    float4 g[8]; float4 w[7];
#pragma unroll
    for (int b = 0; b < 8; ++b) g[b] = *(const float4*)(gated + (size_t)b * D_DIM + i);
#pragma unroll
    for (int m = 0; m < 7; ++m) w[m] = *(const float4*)(Wr + (size_t)m * D_DIM + i);
#pragma unroll
    for (int m = 0; m < 7; ++m)
#pragma unroll
      for (int b = 0; b < 8; ++b)
        acc[m * 8 + b] += w[m].x * g[b].x + w[m].y * g[b].y + w[m].z * g[b].z + w[m].w * g[b].w;
  }
  __shared__ float Ls[56];
#pragma unroll
  for (int t = 0; t < 56; ++t) {
    float v = acc[t];
    v += __shfl_xor(v, 1); v += __shfl_xor(v, 2); v += __shfl_xor(v, 4);
    v += __shfl_xor(v, 8); v += __shfl_xor(v, 16); v += __shfl_xor(v, 32);
    if (lane == t) Ls[t] = v;
  }
  __syncthreads();
  if (lane < 8) {
    const int b = lane;
    float mx = -1e30f;
    for (int m = 0; m < 7; ++m) mx = fmaxf(mx, Ls[m * 8 + b]);
    float s = 0.f;
    for (int m = 0; m < 7; ++m) s += expf(Ls[m * 8 + b] - mx);
    const int mi = midx_p[0];
    const float mp = expf(Ls[mi * 8 + b] - mx) / s;
    int kv = kp[0]; if (kv < 1) kv = 1;
    int klo = kv >> 1; if (klo < 1) klo = 1;
    float sc[4];
#pragma unroll
    for (int e = 0; e < 4; ++e) sc[e] = scores[b * 4 + e];
#pragma unroll
    for (int e = 0; e < 4; ++e) {
      int rank = 0;
#pragma unroll
      for (int e2 = 0; e2 < 4; ++e2)
        rank += (sc[e2] > sc[e] || (sc[e2] == sc[e] && e2 < e)) ? 1 : 0;
      float wv = (mp > 0.5f) ? ((rank < kv) ? 1.0f / (float)kv : 0.f)
                             : ((rank < klo) ? 1.0f / (float)klo : 0.f);
      gate[b * 4 + e] = wv;
    }
  }
}

// ---- K5: LoRA-A projection as MFMA GEMM: t = xa[:, :4096] @ lAb^T (N=32),
// scaled by gate, written bf16 into xa cols 4096..4127. (R3 version, proven.)
__global__ __launch_bounds__(256) void lora_t_k(const short* __restrict__ XA,
                                                const short* __restrict__ LAb,
                                                const float* __restrict__ gate,
                                                short* __restrict__ xa_w) {
  __shared__ short As[4096];   // 64 x 64 bf16
  __shared__ short Bs[2048];   // 32 x 64 bf16
  const int tid = threadIdx.x, lane = tid & 63, wave = tid >> 6;
  const int lo = lane & 15, hi = lane >> 4;
  const size_t row0 = (size_t)blockIdx.x * 64;
  const int srow = tid >> 3;
  const int slot = (tid & 7) ^ (srow & 7);
  const short* gA = XA + (row0 + srow) * (size_t)K_DIM + slot * 8;
  const short* gB = LAb + (size_t)srow * D_DIM + slot * 8;
  f32x4v acc[2] = {};

  for (int t = 0; t < 64; ++t) {
    const int kt = t * 64;
    char* la = (char*)As + wave * 1024;
    char* lb = (char*)Bs + wave * 1024;
    async_copy16(la, gA + kt);
    async_copy16(la + 4096, gA + (size_t)32 * K_DIM + kt);
    async_copy16(lb, gB + kt);
    __syncthreads();
    short8 a0 = frag_ld(As, wave * 16 + lo, 0, hi, lo);
    short8 a1 = frag_ld(As, wave * 16 + lo, 1, hi, lo);
    short8 b00 = frag_ld(Bs, lo, 0, hi, lo);
    short8 b01 = frag_ld(Bs, lo, 1, hi, lo);
    short8 b10 = frag_ld(Bs, 16 + lo, 0, hi, lo);
    short8 b11 = frag_ld(Bs, 16 + lo, 1, hi, lo);
    acc[0] = __builtin_amdgcn_mfma_f32_16x16x32_bf16(a0, b00, acc[0], 0, 0, 0);
    acc[0] = __builtin_amdgcn_mfma_f32_16x16x32_bf16(a1, b01, acc[0], 0, 0, 0);
    acc[1] = __builtin_amdgcn_mfma_f32_16x16x32_bf16(a0, b10, acc[1], 0, 0, 0);
    acc[1] = __builtin_amdgcn_mfma_f32_16x16x32_bf16(a1, b11, acc[1], 0, 0, 0);
    __syncthreads();
  }
  const int b = (int)(row0 >> 11);
#pragma unroll
  for (int ni = 0; ni < 2; ++ni) {
    const int col = ni * 16 + lo;
    const float g = gate[b * 4 + (col >> 3)];
#pragma unroll
    for (int j = 0; j < 4; ++j) {
      const size_t r = row0 + wave * 16 + hi * 4 + j;
      xa_w[r * (size_t)K_DIM + 4096 + col] = (short)f2b(acc[ni][j] * g);
    }
  }
}

// ---- K6: main GEMM. Ring-of-5 K=32 slots (160 KB); barrier + vmcnt(4) every
// TWO groups; each pair is one scheduling region (24 ds_read + 64 MFMA + 8
// gloads) for compiler auto-pipelining. Stage distance d=3.
__global__ __launch_bounds__(512, 2) void gemm_k(const short* __restrict__ A,
                                                 const short* __restrict__ B,
                                                 const float* __restrict__ bias,
                                                 float* __restrict__ C) {
  __shared__ short As[5][8192];   // 5 x 16 KB (256 rows x 32 K)
  __shared__ short Bs[5][8192];
  const int tid = threadIdx.x;
  const int lane = tid & 63;
  const int wave = tid >> 6;            // 0..7
  const int wm = wave >> 2;             // 0..1 -> rows wm*128..+128
  const int wn = wave & 3;              // 0..3 -> cols wn*64..+64
  const int lo = lane & 15, hi = lane >> 4;

  // T1: XCD swizzle (1024 blocks, 8 XCDs, bijective)
  const int wg = (blockIdx.x & 7) * 128 + (blockIdx.x >> 3);
  const int brow = wg >> 4;             // 0..63
  const int bcol = wg & 15;             // 0..15

  // staging: 512 thr x 16 B covers 128 rows x 32 K; row = tid>>2, phys chunk
  // tid&3, logical = phys ^ ((row>>1)&3) = phys ^ ((tid>>3)&3)
  const int srow = tid >> 2;
  const int schunk = (tid & 3) ^ ((tid >> 3) & 3);
  const short* srcA = A + (size_t)(brow * 256 + srow) * K_DIM + schunk * 8;
  const short* srcB = B + (size_t)(bcol * 256 + srow) * K_DIM + schunk * 8;
  char* ldsA0 = (char*)(&As[0][0]) + wave * 1024;  // + slot*16384 + issue*8192
  char* ldsB0 = (char*)(&Bs[0][0]) + wave * 1024;

  // read swizzle: phys chunk = (hi ^ ((lo>>1)&3)), in shorts:
  const int csw = (hi ^ ((lo >> 1) & 3)) * 8;
  const int aro = (wm * 128 + lo) * 32 + csw;      // + mi*512 (+2048 lower half)
  const int bro = (wn * 64 + lo) * 32 + csw;       // + ni*512

  float bz[4];
#pragma unroll
  for (int ni = 0; ni < 4; ++ni)
    bz[ni] = bias[bcol * 256 + wn * 64 + ni * 16 + lo];

  f32x4v acc[8][4] = {};

#define STAGE_A(koff, ss)                                                      \
  async_copy16(ldsA0 + (ss) * 16384, srcA + (koff));                           \
  async_copy16(ldsA0 + (ss) * 16384 + 8192, srcA + (size_t)128 * K_DIM + (koff));
#define STAGE_B(koff, ss)                                                      \
  async_copy16(ldsB0 + (ss) * 16384, srcB + (koff));                           \
  async_copy16(ldsB0 + (ss) * 16384 + 8192, srcB + (size_t)128 * K_DIM + (koff));

// one group: read 12 frags from slot s, MFMA upper, stage, MFMA lower
#define GROUP(s, ko, sw)                                                       \
  {                                                                            \
    const short* Aslot = &As[0][0] + (s) * 8192;                               \
    const short* Bslot = &Bs[0][0] + (s) * 8192;                               \
    short8 afr[4], afr2[4], bfr[4];                                            \
    _Pragma("unroll")                                                          \
    for (int mi = 0; mi < 4; ++mi)                                             \
      afr[mi] = *(const short8*)(&Aslot[aro + mi * 512]);                      \
    _Pragma("unroll")                                                          \
    for (int ni = 0; ni < 4; ++ni)                                             \
      bfr[ni] = *(const short8*)(&Bslot[bro + ni * 512]);                      \
    _Pragma("unroll")                                                          \
    for (int mi = 0; mi < 4; ++mi)                                             \
      afr2[mi] = *(const short8*)(&Aslot[aro + 2048 + mi * 512]);              \
    __builtin_amdgcn_s_setprio(1);                                             \
    _Pragma("unroll")                                                          \
    for (int mi = 0; mi < 4; ++mi)                                             \
      _Pragma("unroll")                                                        \
      for (int ni = 0; ni < 4; ++ni)                                           \
        acc[mi][ni] = __builtin_amdgcn_mfma_f32_16x16x32_bf16(                 \
            afr[mi], bfr[ni], acc[mi][ni], 0, 0, 0);                           \
    __builtin_amdgcn_s_setprio(0);                                             \
    STAGE_A((ko), (sw));                                                       \
    STAGE_B((ko), (sw));                                                       \
    __builtin_amdgcn_s_setprio(1);                                             \
    _Pragma("unroll")                                                          \
    for (int mi = 0; mi < 4; ++mi)                                             \
      _Pragma("unroll")                                                        \
      for (int ni = 0; ni < 4; ++ni)                                           \
        acc[mi + 4][ni] = __builtin_amdgcn_mfma_f32_16x16x32_bf16(             \
            afr2[mi], bfr[ni], acc[mi + 4][ni], 0, 0, 0);                      \
    __builtin_amdgcn_s_setprio(0);                                             \
  }

  // prologue: stage groups 0,1,2 into slots 0,1,2 (12 loads/wave);
  // vmcnt(4) -> stages 0,1 landed (slot 2 in flight)
  STAGE_A(0, 0);  STAGE_B(0, 0);
  STAGE_A(32, 1); STAGE_B(32, 1);
  STAGE_A(64, 2); STAGE_B(64, 2);
  asm volatile("s_waitcnt vmcnt(4)" ::: "memory");
  __builtin_amdgcn_s_barrier();

  int s0 = 0;   // slot of group 2p
  for (int p = 0; p < 65; ++p) {
    const int g0 = 2 * p, g1 = g0 + 1;
    const int s1  = (s0 + 1 == 5) ? 0 : s0 + 1;
    const int sw0 = (s0 + 3 >= 5) ? s0 - 2 : s0 + 3;   // (g0+3)%5
    const int sw1 = (sw0 + 1 == 5) ? 0 : sw0 + 1;      // (g1+3)%5
    const size_t ko0 = (size_t)((g0 + 3 <= NGRP - 1) ? g0 + 3 : g0 - 2) * 32;
    const size_t ko1 = (size_t)((g1 + 3 <= NGRP - 1) ? g1 + 3 : g1 - 2) * 32;

    GROUP(s0, ko0, sw0)
    GROUP(s1, ko1, sw1)

    asm volatile("s_waitcnt vmcnt(4)" ::: "memory");  // stage(2p+3) landed
    __builtin_amdgcn_s_barrier();
    s0 = (s0 + 2 >= 5) ? s0 - 3 : s0 + 2;
  }
  asm volatile("s_waitcnt vmcnt(0)" ::: "memory");    // drain dead stages

#pragma unroll
  for (int mi = 0; mi < 8; ++mi) {
#pragma unroll
    for (int ni = 0; ni < 4; ++ni) {
      const int r0 = brow * 256 + wm * 128 + mi * 16 + hi * 4;
      const int c0 = bcol * 256 + wn * 64 + ni * 16 + lo;
#pragma unroll
      for (int j = 0; j < 4; ++j)
        C[(size_t)(r0 + j) * N_DIM + c0] = acc[mi][ni][j] + bz[ni];
    }
  }
#undef GROUP
#undef STAGE_A
#undef STAGE_B
}

extern "C" void kernel_launch(void* const* d_in, const int* in_sizes, int n_in,
                              void* d_out, int out_size, void* d_ws, size_t ws_size,
                              hipStream_t stream) {
  const float* x      = (const float*)d_in[0];
  const float* scores = (const float*)d_in[1];
  const float* Wb     = (const float*)d_in[2];
  const float* bb     = (const float*)d_in[3];
  const float* gW     = (const float*)d_in[4];
  const float* Wr     = (const float*)d_in[5];
  const float* lA     = (const float*)d_in[6];
  const float* lB     = (const float*)d_in[7];
  const int*   midx   = (const int*)d_in[8];
  const int*   kk     = (const int*)d_in[9];
  float* out = (float*)d_out;

  char* ws = (char*)d_ws;
  short* xa    = (short*)ws;                                        // 136,314,880 B
  short* wa    = (short*)(ws + 136314880u);                         //  34,078,720 B
  float* gated = (float*)(ws + 136314880u + 34078720u);             //     131,072 B
  float* gate  = (float*)(ws + 136314880u + 34078720u + 131072u);   //         128 B
  short* lAb   = (short*)(ws + 136314880u + 34078720u + 131072u + 128u);  // 262,144 B

  cvt_x_k<<<33280, 256, 0, stream>>>(x, xa);
  cvt_w_k<<<8320, 256, 0, stream>>>(Wb, lB, wa);
  cvt_la_k<<<64, 256, 0, stream>>>(lA, lAb);
  gated_k<<<4096, 256, 0, stream>>>(x, gW, gated);
  gate_k<<<1, 64, 0, stream>>>(gated, Wr, scores, midx, kk, gate);
  lora_t_k<<<256, 256, 0, stream>>>(xa, lAb, gate, xa);
  gemm_k<<<1024, 512, 0, stream>>>(xa, wa, bb, out);
}

// Round 9
// 705.634 us; speedup vs baseline: 1.2506x; 1.0004x over previous
//
#include <hip/hip_runtime.h>
#include <hip/hip_bf16.h>

// DynaLoRALinear via K-augmented bf16 GEMM:
//   x_aug[row][0:4096]=bf16(x), [4096:4128]=gate*t, [4128:4160]=0
//   W_aug[o][0:4096]=bf16(W_base), [4096+e*8+r]=bf16(lora_B[e,o,r]), rest 0
//   out = x_aug @ W_aug^T + b_base   (M=16384, N=4096, K=4160)
// GEMM R8: 256x256 tile, 8 waves, ring-of-5 K=32 slots (160 KB LDS), barrier
// every 2 groups (65 barriers): each region = {24 ds_read || 64 MFMA || 8
// gloads} -> compiler auto-pipelines group 2p+1 reads into group 2p MFMAs.
// vmcnt(4) per pair (stage(2p+3) landed, 2p+4 in flight). Safety: S=5 >= d+B
// = 3+2; read slots {2p,2p+1}%5 disjoint from write slots {2p+3,2p+4}%5.

typedef short short8 __attribute__((ext_vector_type(8)));
typedef float f32x4v __attribute__((ext_vector_type(4)));

#define M_DIM 16384
#define N_DIM 4096
#define K_DIM 4160   // 65 * 64 = 130 * 32
#define D_DIM 4096
#define NGRP 130     // 32-wide K groups

__device__ __forceinline__ unsigned short f2b(float f) {
  unsigned u = __builtin_bit_cast(unsigned, f);
  return (unsigned short)((u + 0x7FFFu + ((u >> 16) & 1u)) >> 16);  // RNE
}
__device__ __forceinline__ void async_copy16(void* lds, const void* g) {
  __builtin_amdgcn_global_load_lds(
      (const __attribute__((address_space(1))) void*)g,
      (__attribute__((address_space(3))) void*)lds, 16, 0, 0);
}
// 64-col (128 B-row) LDS tiles (lora_t kernel): phys 16B-slot p of row r holds
// logical l = p ^ (r&7); read logical l at p = l ^ (r&7).
__device__ __forceinline__ short8 frag_ld(const short* base, int row, int ks, int hi, int lo) {
  return *(const short8*)(&base[row * 64 + (((ks * 4 + hi) ^ (lo & 7)) * 8)]);
}

// ---- K1: x (f32) -> x_aug (bf16, stride 4160), zero cols 4096..4159
__global__ __launch_bounds__(256) void cvt_x_k(const float* __restrict__ x,
                                               short* __restrict__ xa) {
  size_t idx = (size_t)blockIdx.x * 256 + threadIdx.x;   // 16384*520
  size_t row = idx / 520;
  int cc = (int)(idx % 520);
  short8 o;
  if (cc < 512) {
    const float* src = x + row * (size_t)D_DIM + (size_t)cc * 8;
    float4 a = *(const float4*)(src);
    float4 b = *(const float4*)(src + 4);
    o[0] = (short)f2b(a.x); o[1] = (short)f2b(a.y);
    o[2] = (short)f2b(a.z); o[3] = (short)f2b(a.w);
    o[4] = (short)f2b(b.x); o[5] = (short)f2b(b.y);
    o[6] = (short)f2b(b.z); o[7] = (short)f2b(b.w);
  } else {
#pragma unroll
    for (int t = 0; t < 8; ++t) o[t] = 0;
  }
  *(short8*)(xa + row * (size_t)K_DIM + (size_t)cc * 8) = o;
}

// ---- K2: W_base -> W_aug, pack lora_B into cols 4096..4127, zero rest
__global__ __launch_bounds__(256) void cvt_w_k(const float* __restrict__ Wb,
                                               const float* __restrict__ lB,
                                               short* __restrict__ wa) {
  size_t idx = (size_t)blockIdx.x * 256 + threadIdx.x;   // 4096*520
  size_t row = idx / 520;
  int cc = (int)(idx % 520);
  short8 o;
  if (cc < 512) {
    const float* src = Wb + row * (size_t)D_DIM + (size_t)cc * 8;
    float4 a = *(const float4*)(src);
    float4 b = *(const float4*)(src + 4);
    o[0] = (short)f2b(a.x); o[1] = (short)f2b(a.y);
    o[2] = (short)f2b(a.z); o[3] = (short)f2b(a.w);
    o[4] = (short)f2b(b.x); o[5] = (short)f2b(b.y);
    o[6] = (short)f2b(b.z); o[7] = (short)f2b(b.w);
  } else if (cc < 516) {
    int e = cc - 512;
    const float* src = lB + (size_t)e * (D_DIM * 8) + row * 8;
    float4 a = *(const float4*)(src);
    float4 b = *(const float4*)(src + 4);
    o[0] = (short)f2b(a.x); o[1] = (short)f2b(a.y);
    o[2] = (short)f2b(a.z); o[3] = (short)f2b(a.w);
    o[4] = (short)f2b(b.x); o[5] = (short)f2b(b.y);
    o[6] = (short)f2b(b.z); o[7] = (short)f2b(b.w);
  } else {
#pragma unroll
    for (int t = 0; t < 8; ++t) o[t] = 0;
  }
  *(short8*)(wa + row * (size_t)K_DIM + (size_t)cc * 8) = o;
}

// ---- K2b: lora_A (f32 [32][4096]) -> bf16
__global__ __launch_bounds__(256) void cvt_la_k(const float* __restrict__ lA,
                                                short* __restrict__ lAb) {
  size_t i = (size_t)blockIdx.x * 256 + threadIdx.x;
  const float* s = lA + i * 8;
  float4 a = *(const float4*)s;
  float4 b = *(const float4*)(s + 4);
  short8 o;
  o[0] = (short)f2b(a.x); o[1] = (short)f2b(a.y);
  o[2] = (short)f2b(a.z); o[3] = (short)f2b(a.w);
  o[4] = (short)f2b(b.x); o[5] = (short)f2b(b.y);
  o[6] = (short)f2b(b.z); o[7] = (short)f2b(b.w);
  *(short8*)(lAb + i * 8) = o;
}

// ---- K3: gated[b][j] = dot(x[b,L-1,:], gating_W[j,:]) (exact f32 path)
__global__ __launch_bounds__(256) void gated_k(const float* __restrict__ x,
                                               const float* __restrict__ gW,
                                               float* __restrict__ gated) {
  const int j = blockIdx.x;
  const int tid = threadIdx.x;
  float acc[8];
#pragma unroll
  for (int b = 0; b < 8; ++b) acc[b] = 0.f;
  const float* w = gW + (size_t)j * D_DIM;
  for (int i = tid * 4; i < D_DIM; i += 1024) {
    float4 wv = *(const float4*)(w + i);
#pragma unroll
    for (int b = 0; b < 8; ++b) {
      const float* p = x + ((size_t)b * 2048 + 2047) * D_DIM + i;
      float4 pv = *(const float4*)p;
      acc[b] += wv.x * pv.x + wv.y * pv.y + wv.z * pv.z + wv.w * pv.w;
    }
  }
  __shared__ float red[8][4];
  const int lane = tid & 63, wv_ = tid >> 6;
#pragma unroll
  for (int b = 0; b < 8; ++b) {
    float v = acc[b];
    v += __shfl_down(v, 32); v += __shfl_down(v, 16); v += __shfl_down(v, 8);
    v += __shfl_down(v, 4);  v += __shfl_down(v, 2);  v += __shfl_down(v, 1);
    if (lane == 0) red[b][wv_] = v;
  }
  __syncthreads();
  if (tid < 8)
    gated[(size_t)tid * D_DIM + j] = red[tid][0] + red[tid][1] + red[tid][2] + red[tid][3];
}

// ---- K4: logits -> softmax -> module_prob -> top-k gate (1 wave)
__global__ void gate_k(const float* __restrict__ gated, const float* __restrict__ Wr,
                       const float* __restrict__ scores, const int* __restrict__ midx_p,
                       const int* __restrict__ kp, float* __restrict__ gate) {
  const int lane = threadIdx.x;
  float acc[56];
#pragma unroll
  for (int t = 0; t < 56; ++t) acc[t] = 0.f;
  for (int i = lane * 4; i < D_DIM; i += 256) {
    float4 g[8]; float4 w[7];
#pragma unroll
    for (int b = 0; b < 8; ++b) g[b] = *(const float4*)(gated + (size_t)b * D_DIM + i);
#pragma unroll
    for (int m = 0; m < 7; ++m) w[m] = *(const float4*)(Wr + (size_t)m * D_DIM + i);
#pragma unroll
    for (int m = 0; m < 7; ++m)
#pragma unroll
      for (int b = 0; b < 8; ++b)
        acc[m * 8 + b] += w[m].x * g[b].x + w[m].y * g[b].y + w[m].z * g[b].z + w[m].w * g[b].w;
  }
  __shared__ float Ls[56];
#pragma unroll
  for (int t = 0; t < 56; ++t) {
    float v = acc[t];
    v += __shfl_xor(v, 1); v += __shfl_xor(v, 2); v += __shfl_xor(v, 4);
    v += __shfl_xor(v, 8); v += __shfl_xor(v, 16); v += __shfl_xor(v, 32);
    if (lane == t) Ls[t] = v;
  }
  __syncthreads();
  if (lane < 8) {
    const int b = lane;
    float mx = -1e30f;
    for (int m = 0; m < 7; ++m) mx = fmaxf(mx, Ls[m * 8 + b]);
    float s = 0.f;
    for (int m = 0; m < 7; ++m) s += expf(Ls[m * 8 + b] - mx);
    const int mi = midx_p[0];
    const float mp = expf(Ls[mi * 8 + b] - mx) / s;
    int kv = kp[0]; if (kv < 1) kv = 1;
    int klo = kv >> 1; if (klo < 1) klo = 1;
    float sc[4];
#pragma unroll
    for (int e = 0; e < 4; ++e) sc[e] = scores[b * 4 + e];
#pragma unroll
    for (int e = 0; e < 4; ++e) {
      int rank = 0;
#pragma unroll
      for (int e2 = 0; e2 < 4; ++e2)
        rank += (sc[e2] > sc[e] || (sc[e2] == sc[e] && e2 < e)) ? 1 : 0;
      float wv = (mp > 0.5f) ? ((rank < kv) ? 1.0f / (float)kv : 0.f)
                             : ((rank < klo) ? 1.0f / (float)klo : 0.f);
      gate[b * 4 + e] = wv;
    }
  }
}

// ---- K5: LoRA-A projection as MFMA GEMM: t = xa[:, :4096] @ lAb^T (N=32),
// scaled by gate, written bf16 into xa cols 4096..4127. (R3 version, proven.)
__global__ __launch_bounds__(256) void lora_t_k(const short* __restrict__ XA,
                                                const short* __restrict__ LAb,
                                                const float* __restrict__ gate,
                                                short* __restrict__ xa_w) {
  __shared__ short As[4096];   // 64 x 64 bf16
  __shared__ short Bs[2048];   // 32 x 64 bf16
  const int tid = threadIdx.x, lane = tid & 63, wave = tid >> 6;
  const int lo = lane & 15, hi = lane >> 4;
  const size_t row0 = (size_t)blockIdx.x * 64;
  const int srow = tid >> 3;
  const int slot = (tid & 7) ^ (srow & 7);
  const short* gA = XA + (row0 + srow) * (size_t)K_DIM + slot * 8;
  const short* gB = LAb + (size_t)srow * D_DIM + slot * 8;
  f32x4v acc[2] = {};

  for (int t = 0; t < 64; ++t) {
    const int kt = t * 64;
    char* la = (char*)As + wave * 1024;
    char* lb = (char*)Bs + wave * 1024;
    async_copy16(la, gA + kt);
    async_copy16(la + 4096, gA + (size_t)32 * K_DIM + kt);
    async_copy16(lb, gB + kt);
    __syncthreads();
    short8 a0 = frag_ld(As, wave * 16 + lo, 0, hi, lo);
    short8 a1 = frag_ld(As, wave * 16 + lo, 1, hi, lo);
    short8 b00 = frag_ld(Bs, lo, 0, hi, lo);
    short8 b01 = frag_ld(Bs, lo, 1, hi, lo);
    short8 b10 = frag_ld(Bs, 16 + lo, 0, hi, lo);
    short8 b11 = frag_ld(Bs, 16 + lo, 1, hi, lo);
    acc[0] = __builtin_amdgcn_mfma_f32_16x16x32_bf16(a0, b00, acc[0], 0, 0, 0);
    acc[0] = __builtin_amdgcn_mfma_f32_16x16x32_bf16(a1, b01, acc[0], 0, 0, 0);
    acc[1] = __builtin_amdgcn_mfma_f32_16x16x32_bf16(a0, b10, acc[1], 0, 0, 0);
    acc[1] = __builtin_amdgcn_mfma_f32_16x16x32_bf16(a1, b11, acc[1], 0, 0, 0);
    __syncthreads();
  }
  const int b = (int)(row0 >> 11);
#pragma unroll
  for (int ni = 0; ni < 2; ++ni) {
    const int col = ni * 16 + lo;
    const float g = gate[b * 4 + (col >> 3)];
#pragma unroll
    for (int j = 0; j < 4; ++j) {
      const size_t r = row0 + wave * 16 + hi * 4 + j;
      xa_w[r * (size_t)K_DIM + 4096 + col] = (short)f2b(acc[ni][j] * g);
    }
  }
}

// ---- K6: main GEMM. Ring-of-5 K=32 slots (160 KB); barrier + vmcnt(4) every
// TWO groups; each pair is one scheduling region (24 ds_read + 64 MFMA + 8
// gloads) for compiler auto-pipelining. Stage distance d=3.
__global__ __launch_bounds__(512, 2) void gemm_k(const short* __restrict__ A,
                                                 const short* __restrict__ B,
                                                 const float* __restrict__ bias,
                                                 float* __restrict__ C) {
  __shared__ short As[5][8192];   // 5 x 16 KB (256 rows x 32 K)
  __shared__ short Bs[5][8192];
  const int tid = threadIdx.x;
  const int lane = tid & 63;
  const int wave = tid >> 6;            // 0..7
  const int wm = wave >> 2;             // 0..1 -> rows wm*128..+128
  const int wn = wave & 3;              // 0..3 -> cols wn*64..+64
  const int lo = lane & 15, hi = lane >> 4;

  // T1: XCD swizzle (1024 blocks, 8 XCDs, bijective)
  const int wg = (blockIdx.x & 7) * 128 + (blockIdx.x >> 3);
  const int brow = wg >> 4;             // 0..63
  const int bcol = wg & 15;             // 0..15

  // staging: 512 thr x 16 B covers 128 rows x 32 K; row = tid>>2, phys chunk
  // tid&3, logical = phys ^ ((row>>1)&3) = phys ^ ((tid>>3)&3)
  const int srow = tid >> 2;
  const int schunk = (tid & 3) ^ ((tid >> 3) & 3);
  const short* srcA = A + (size_t)(brow * 256 + srow) * K_DIM + schunk * 8;
  const short* srcB = B + (size_t)(bcol * 256 + srow) * K_DIM + schunk * 8;
  char* ldsA0 = (char*)(&As[0][0]) + wave * 1024;  // + slot*16384 + issue*8192
  char* ldsB0 = (char*)(&Bs[0][0]) + wave * 1024;

  // read swizzle: phys chunk = (hi ^ ((lo>>1)&3)), in shorts:
  const int csw = (hi ^ ((lo >> 1) & 3)) * 8;
  const int aro = (wm * 128 + lo) * 32 + csw;      // + mi*512 (+2048 lower half)
  const int bro = (wn * 64 + lo) * 32 + csw;       // + ni*512

  float bz[4];
#pragma unroll
  for (int ni = 0; ni < 4; ++ni)
    bz[ni] = bias[bcol * 256 + wn * 64 + ni * 16 + lo];

  f32x4v acc[8][4] = {};

#define STAGE_A(koff, ss)                                                      \
  async_copy16(ldsA0 + (ss) * 16384, srcA + (koff));                           \
  async_copy16(ldsA0 + (ss) * 16384 + 8192, srcA + (size_t)128 * K_DIM + (koff));
#define STAGE_B(koff, ss)                                                      \
  async_copy16(ldsB0 + (ss) * 16384, srcB + (koff));                           \
  async_copy16(ldsB0 + (ss) * 16384 + 8192, srcB + (size_t)128 * K_DIM + (koff));

// one group: read 12 frags from slot s, MFMA upper, stage, MFMA lower
#define GROUP(s, ko, sw)                                                       \
  {                                                                            \
    const short* Aslot = &As[0][0] + (s) * 8192;                               \
    const short* Bslot = &Bs[0][0] + (s) * 8192;                               \
    short8 afr[4], afr2[4], bfr[4];                                            \
    _Pragma("unroll")                                                          \
    for (int mi = 0; mi < 4; ++mi)                                             \
      afr[mi] = *(const short8*)(&Aslot[aro + mi * 512]);                      \
    _Pragma("unroll")                                                          \
    for (int ni = 0; ni < 4; ++ni)                                             \
      bfr[ni] = *(const short8*)(&Bslot[bro + ni * 512]);                      \
    _Pragma("unroll")                                                          \
    for (int mi = 0; mi < 4; ++mi)                                             \
      afr2[mi] = *(const short8*)(&Aslot[aro + 2048 + mi * 512]);              \
    __builtin_amdgcn_s_setprio(1);                                             \
    _Pragma("unroll")                                                          \
    for (int mi = 0; mi < 4; ++mi)                                             \
      _Pragma("unroll")                                                        \
      for (int ni = 0; ni < 4; ++ni)                                           \
        acc[mi][ni] = __builtin_amdgcn_mfma_f32_16x16x32_bf16(                 \
            afr[mi], bfr[ni], acc[mi][ni], 0, 0, 0);                           \
    __builtin_amdgcn_s_setprio(0);                                             \
    STAGE_A((ko), (sw));                                                       \
    STAGE_B((ko), (sw));                                                       \
    __builtin_amdgcn_s_setprio(1);                                             \
    _Pragma("unroll")                                                          \
    for (int mi = 0; mi < 4; ++mi)                                             \
      _Pragma("unroll")                                                        \
      for (int ni = 0; ni < 4; ++ni)                                           \
        acc[mi + 4][ni] = __builtin_amdgcn_mfma_f32_16x16x32_bf16(             \
            afr2[mi], bfr[ni], acc[mi + 4][ni], 0, 0, 0);                      \
    __builtin_amdgcn_s_setprio(0);                                             \
  }

  // prologue: stage groups 0,1,2 into slots 0,1,2 (12 loads/wave);
  // vmcnt(4) -> stages 0,1 landed (slot 2 in flight)
  STAGE_A(0, 0);  STAGE_B(0, 0);
  STAGE_A(32, 1); STAGE_B(32, 1);
  STAGE_A(64, 2); STAGE_B(64, 2);
  asm volatile("s_waitcnt vmcnt(4)" ::: "memory");
  __builtin_amdgcn_s_barrier();

  int s0 = 0;   // slot of group 2p
  for (int p = 0; p < 65; ++p) {
    const int g0 = 2 * p, g1 = g0 + 1;
    const int s1  = (s0 + 1 == 5) ? 0 : s0 + 1;
    const int sw0 = (s0 + 3 >= 5) ? s0 - 2 : s0 + 3;   // (g0+3)%5
    const int sw1 = (sw0 + 1 == 5) ? 0 : sw0 + 1;      // (g1+3)%5
    const size_t ko0 = (size_t)((g0 + 3 <= NGRP - 1) ? g0 + 3 : g0 - 2) * 32;
    const size_t ko1 = (size_t)((g1 + 3 <= NGRP - 1) ? g1 + 3 : g1 - 2) * 32;

    GROUP(s0, ko0, sw0)
    GROUP(s1, ko1, sw1)

    asm volatile("s_waitcnt vmcnt(4)" ::: "memory");  // stage(2p+3) landed
    __builtin_amdgcn_s_barrier();
    s0 = (s0 + 2 >= 5) ? s0 - 3 : s0 + 2;
  }
  asm volatile("s_waitcnt vmcnt(0)" ::: "memory");    // drain dead stages

#pragma unroll
  for (int mi = 0; mi < 8; ++mi) {
#pragma unroll
    for (int ni = 0; ni < 4; ++ni) {
      const int r0 = brow * 256 + wm * 128 + mi * 16 + hi * 4;
      const int c0 = bcol * 256 + wn * 64 + ni * 16 + lo;
#pragma unroll
      for (int j = 0; j < 4; ++j)
        C[(size_t)(r0 + j) * N_DIM + c0] = acc[mi][ni][j] + bz[ni];
    }
  }
#undef GROUP
#undef STAGE_A
#undef STAGE_B
}

extern "C" void kernel_launch(void* const* d_in, const int* in_sizes, int n_in,
                              void* d_out, int out_size, void* d_ws, size_t ws_size,
                              hipStream_t stream) {
  const float* x      = (const float*)d_in[0];
  const float* scores = (const float*)d_in[1];
  const float* Wb     = (const float*)d_in[2];
  const float* bb     = (const float*)d_in[3];
  const float* gW     = (const float*)d_in[4];
  const float* Wr     = (const float*)d_in[5];
  const float* lA     = (const float*)d_in[6];
  const float* lB     = (const float*)d_in[7];
  const int*   midx   = (const int*)d_in[8];
  const int*   kk     = (const int*)d_in[9];
  float* out = (float*)d_out;

  char* ws = (char*)d_ws;
  short* xa    = (short*)ws;                                        // 136,314,880 B
  short* wa    = (short*)(ws + 136314880u);                         //  34,078,720 B
  float* gated = (float*)(ws + 136314880u + 34078720u);             //     131,072 B
  float* gate  = (float*)(ws + 136314880u + 34078720u + 131072u);   //         128 B
  short* lAb   = (short*)(ws + 136314880u + 34078720u + 131072u + 128u);  // 262,144 B

  cvt_x_k<<<33280, 256, 0, stream>>>(x, xa);
  cvt_w_k<<<8320, 256, 0, stream>>>(Wb, lB, wa);
  cvt_la_k<<<64, 256, 0, stream>>>(lA, lAb);
  gated_k<<<4096, 256, 0, stream>>>(x, gW, gated);
  gate_k<<<1, 64, 0, stream>>>(gated, Wr, scores, midx, kk, gate);
  lora_t_k<<<256, 256, 0, stream>>>(xa, lAb, gate, xa);
  gemm_k<<<1024, 512, 0, stream>>>(xa, wa, bb, out);
}